// Round 2
// 1464.626 us; speedup vs baseline: 1.0469x; 1.0469x over previous
//
#include <hip/hip_runtime.h>
#include <hip/hip_bf16.h>

// ---------------- output layout constants (floats) ----------------
constexpr size_t OFF_W1 = 1;
constexpr size_t OFF_B1 = OFF_W1 + (size_t)1024*32768;
constexpr size_t OFF_W2 = OFF_B1 + (size_t)1024*256;
constexpr size_t OFF_B2 = OFF_W2 + (size_t)1024*65536;
constexpr size_t OFF_W3 = OFF_B2 + (size_t)1024*256;
constexpr size_t OFF_B3 = OFF_W3 + (size_t)1024*32768;

// ================= generic f32 GEMM (a1/a2/encoder only) =================
__global__ __launch_bounds__(256) void gemm_kernel(
    const float* __restrict__ A, int lda,
    const float* __restrict__ W, int ldw,
    const float* __restrict__ bias,
    float* __restrict__ C, int ldc,
    int N, int K, int do_relu)
{
    __shared__ float As[16][65];
    __shared__ float Ws[16][65];
    const int tid = threadIdx.x;
    const int tx = tid & 15, ty = tid >> 4;
    const int m0 = blockIdx.x * 64, n0 = blockIdx.y * 64;
    float acc[4][4] = {};
    for (int k0 = 0; k0 < K; k0 += 16) {
        for (int l = tid; l < 1024; l += 256) {
            int mm = l >> 4, kk = l & 15;
            int gk = k0 + kk;
            As[kk][mm] = (gk < K) ? A[(size_t)(m0+mm)*lda + gk] : 0.f;
        }
        for (int l = tid; l < 1024; l += 256) {
            int kk = l >> 6, nn = l & 63;
            int gk = k0 + kk, gn = n0 + nn;
            Ws[kk][nn] = (gk < K && gn < N) ? W[(size_t)gk*ldw + gn] : 0.f;
        }
        __syncthreads();
        #pragma unroll
        for (int kk = 0; kk < 16; ++kk) {
            float a[4], b[4];
            #pragma unroll
            for (int i=0;i<4;i++) a[i] = As[kk][ty*4+i];
            #pragma unroll
            for (int j=0;j<4;j++) b[j] = Ws[kk][tx*4+j];
            #pragma unroll
            for (int i=0;i<4;i++)
                #pragma unroll
                for (int j=0;j<4;j++)
                    acc[i][j] = fmaf(a[i], b[j], acc[i][j]);
        }
        __syncthreads();
    }
    #pragma unroll
    for (int i=0;i<4;i++){
        int gm = m0 + ty*4 + i;
        #pragma unroll
        for (int j=0;j<4;j++){
            int gn = n0 + tx*4 + j;
            if (gn < N) {
                float v = acc[i][j] + (bias ? bias[gn] : 0.f);
                if (do_relu) v = fmaxf(v, 0.f);
                C[(size_t)gm*ldc + gn] = v;
            }
        }
    }
}

// ================= prep: tW3 transpose (for col-major trans), T2/T3, acc zero ====
// blocks 0..255: tW3 tiles (k=bid>>1, i-half=bid&1); 256..511: T2; 512..639: T3; 640: zero
__global__ __launch_bounds__(256) void prep_kernel(
    const float* __restrict__ tW3,
    const float* __restrict__ mW2, const float* __restrict__ mW3,
    float* __restrict__ tW3T,
    float* __restrict__ T2, float* __restrict__ T3,
    float* __restrict__ acc)
{
    __shared__ float tile[64*129];
    const int t = threadIdx.x;
    const int bid = blockIdx.x;
    if (bid < 256) {
        const int k = bid >> 1, i0 = (bid & 1) * 64;
        const size_t base = (size_t)k << 14;
        for (int l = t; l < 8192; l += 256) {
            int ii = l >> 7, jj = l & 127;
            tile[ii*129 + jj] = tW3[base + (size_t)(i0+ii)*128 + jj];
        }
        __syncthreads();
        for (int l = t; l < 8192; l += 256) {
            int jj = l >> 6, ii = l & 63;
            tW3T[base + (size_t)jj*128 + i0 + ii] = tile[ii*129 + jj];
        }
    } else if (bid < 512) {
        const int c = bid - 256;
        T2[(size_t)c*256 + t] = mW2[(size_t)t*256 + c];
    } else if (bid < 640) {
        const int c = bid - 512;
        T3[(size_t)c*256 + t] = mW3[(size_t)t*128 + c];
    } else {
        if (t < 16) acc[t] = 0.f;
    }
}

// ================= dedicated K=128 GEMM: 32x256 tile, A broadcast from LDS ========
// C[m][n] = sum_k A[m][k]*W[k][n] + bias[n]; grid (M/32, N/256), 256 thr
// bias_mode 0: bias[n] direct (float4). bias_mode 1: bias stored transposed
//   (bias index = (n&127)*128 + (n>>7)) — used for tb3 with col-major trans output.
__device__ __forceinline__ void gemm_k128_compute(
    const float* __restrict__ A, int lda, const float* __restrict__ W,
    const float* __restrict__ bias, int bias_mode, int N, int m0, int n0, int t,
    float* __restrict__ As, float4* __restrict__ acc)
{
    // stage A^T into LDS: As[k][r], pad 36 so r0 in {0,8,16,24} stays 16B-aligned
    for (int l = t; l < 4096; l += 256) {
        int r = l >> 7, k = l & 127;
        As[k*36 + r] = A[(size_t)(m0 + r)*lda + k];
    }
    __syncthreads();
    const int c4 = (t & 63) * 4;
    const int r0 = (t >> 6) * 8;
    float4 bv;
    if (bias_mode == 0) {
        bv = *(const float4*)&bias[n0 + c4];
    } else {
        const int n = n0 + c4;                 // n..n+3 share j = n>>7
        const int j = n >> 7, i = n & 127;
        bv.x = bias[(size_t)(i+0)*128 + j];
        bv.y = bias[(size_t)(i+1)*128 + j];
        bv.z = bias[(size_t)(i+2)*128 + j];
        bv.w = bias[(size_t)(i+3)*128 + j];
    }
    #pragma unroll
    for (int i = 0; i < 8; ++i) acc[i] = bv;
    const float* Wp = W + (size_t)n0 + c4;
    #pragma unroll 4
    for (int k = 0; k < 128; ++k) {
        float4 w = *(const float4*)&Wp[(size_t)k*N];   // coalesced 1KB/wave
        float a[8];
        *(float4*)&a[0] = *(const float4*)&As[k*36 + r0];     // wave-uniform broadcast
        *(float4*)&a[4] = *(const float4*)&As[k*36 + r0 + 4];
        #pragma unroll
        for (int i = 0; i < 8; ++i) {
            acc[i].x = fmaf(w.x, a[i], acc[i].x);
            acc[i].y = fmaf(w.y, a[i], acc[i].y);
            acc[i].z = fmaf(w.z, a[i], acc[i].z);
            acc[i].w = fmaf(w.w, a[i], acc[i].w);
        }
    }
}

__global__ __launch_bounds__(256) void gemm_k128_kernel(
    const float* __restrict__ A, int lda, const float* __restrict__ W,
    const float* __restrict__ bias, int bias_mode, float* __restrict__ C, int N)
{
    __shared__ float As[128*36];
    float4 acc[8];
    const int t = threadIdx.x;
    const int m0 = blockIdx.x * 32, n0 = blockIdx.y * 256;
    gemm_k128_compute(A, lda, W, bias, bias_mode, N, m0, n0, t, As, acc);
    const int c4 = (t & 63) * 4;
    const int r0 = (t >> 6) * 8;
    #pragma unroll
    for (int i = 0; i < 8; ++i)
        *(float4*)&C[(size_t)(m0 + r0 + i)*N + n0 + c4] = acc[i];
}

// same GEMM but fused MSE vs ref (skips materializing C)
__global__ __launch_bounds__(256) void gemm_k128_mse_kernel(
    const float* __restrict__ A, int lda, const float* __restrict__ W,
    const float* __restrict__ bias, const float* __restrict__ ref, int N,
    float scale, float* __restrict__ accum)
{
    __shared__ float As[128*36];
    float4 acc[8];
    const int t = threadIdx.x;
    const int m0 = blockIdx.x * 32, n0 = blockIdx.y * 256;
    gemm_k128_compute(A, lda, W, bias, 0, N, m0, n0, t, As, acc);
    const int c4 = (t & 63) * 4;
    const int r0 = (t >> 6) * 8;
    float s = 0.f;
    #pragma unroll
    for (int i = 0; i < 8; ++i) {
        float4 rv = *(const float4*)&ref[(size_t)(m0 + r0 + i)*N + n0 + c4];
        float dx = acc[i].x - rv.x, dy = acc[i].y - rv.y;
        float dz = acc[i].z - rv.z, dw = acc[i].w - rv.w;
        s += dx*dx + dy*dy + dz*dz + dw*dw;
    }
    #pragma unroll
    for (int off = 32; off > 0; off >>= 1) s += __shfl_down(s, off, 64);
    __shared__ float wred[4];
    if ((t & 63) == 0) wred[t >> 6] = s;
    __syncthreads();
    if (t == 0) atomicAdd(accum, (wred[0]+wred[1]+wred[2]+wred[3]) * scale);
}

// ================= scan v3: col-major trans, lane-local i-contraction =================
// 8 blocks x 512 thr. thread: j=tid>>2 owns output col j, p=tid&3 owns i-chunk [p*32,p*32+32)
__global__ __launch_bounds__(512) void scan_kernel3(
    const float* __restrict__ transT,   // (B*S) x 128(j) x 128(i)
    const float* __restrict__ init_hidden,
    float* __restrict__ structural)
{
    __shared__ float h[128];
    __shared__ float ws[8];
    const int b = blockIdx.x, tid = threadIdx.x;
    const int j = tid >> 2, p = tid & 3;
    const int i0 = p * 32;

    if (tid < 32) {
        float4 v = *(const float4*)&init_hidden[tid*4];
        float ss = v.x*v.x + v.y*v.y + v.z*v.z + v.w*v.w;
        ss += __shfl_xor(ss, 16); ss += __shfl_xor(ss, 8); ss += __shfl_xor(ss, 4);
        ss += __shfl_xor(ss, 2);  ss += __shfl_xor(ss, 1);
        float inv = 1.f / fmaxf(sqrtf(ss), 1e-12f);
        v.x *= inv; v.y *= inv; v.z *= inv; v.w *= inv;
        *(float4*)&h[tid*4] = v;
    }
    __syncthreads();

    const size_t bbase = ((size_t)b) << 21;   // b*128*16384
    const int lane_off = j*128 + i0;
    float4 cur[8], nxt[8];
    {
        const float* T0 = transT + bbase + lane_off;
        #pragma unroll
        for (int r = 0; r < 8; ++r) cur[r] = *(const float4*)&T0[r*4];
    }
    for (int t = 0; t < 128; ++t) {
        const int tn = (t < 127) ? t + 1 : 127;
        const float* Tn = transT + bbase + ((size_t)tn << 14) + lane_off;
        #pragma unroll
        for (int r = 0; r < 8; ++r) nxt[r] = *(const float4*)&Tn[r*4];

        float4 a = make_float4(0.f, 0.f, 0.f, 0.f);
        #pragma unroll
        for (int r = 0; r < 8; ++r) {
            float4 hv = *(const float4*)&h[i0 + r*4];
            a.x = fmaf(hv.x, cur[r].x, a.x);
            a.y = fmaf(hv.y, cur[r].y, a.y);
            a.z = fmaf(hv.z, cur[r].z, a.z);
            a.w = fmaf(hv.w, cur[r].w, a.w);
        }
        float s = (a.x + a.y) + (a.z + a.w);
        s += __shfl_xor(s, 1);
        s += __shfl_xor(s, 2);             // all 4 p-lanes: full dot for col j
        float v = fmaxf(s, 0.f);
        float q = v * v;
        q += __shfl_xor(q, 4);  q += __shfl_xor(q, 8);
        q += __shfl_xor(q, 16); q += __shfl_xor(q, 32);  // sum over wave's 16 j's
        if ((tid & 63) == 0) ws[tid >> 6] = q;
        __syncthreads();
        float ss = ((ws[0]+ws[1]) + (ws[2]+ws[3])) + ((ws[4]+ws[5]) + (ws[6]+ws[7]));
        float inv = 1.f / fmaxf(sqrtf(ss), 1e-12f);
        float hv = v * inv;
        __syncthreads();                    // all reads of ws done before reuse
        if (p == 0) h[j] = hv;
        else if (p == 1) structural[(((size_t)(b*128 + t)) << 7) + j] = hv;
        __syncthreads();
        #pragma unroll
        for (int r = 0; r < 8; ++r) cur[r] = nxt[r];
    }
}

// ================= fused-MLP building blocks (unchanged, proven) =================
__device__ __forceinline__ void stage_rows(float* buf, const float* src, int ld,
                                           int row0, int rows, int t)
{
    int r = t >> 5; if (rows == 4) r &= 3;
    const int k4 = (t & 31) * 4;
    float4 v = make_float4(0.f,0.f,0.f,0.f);
    if (src) v = *(const float4*)&src[(size_t)(row0 + r)*ld + k4];
    *(float4*)&buf[r*128 + k4] = v;
}

__device__ __forceinline__ void layer_n256_r8(
    const float* __restrict__ W, const float* __restrict__ bias, int K,
    const float* __restrict__ x, int xs, float* __restrict__ y, int relu, int t)
{
    const int c4 = (t & 63) * 4;
    const int r0 = (t >> 6) * 2;
    float4 a0 = bias ? *(const float4*)&bias[c4] : make_float4(0.f,0.f,0.f,0.f);
    float4 a1 = a0;
    const float* x0 = x + r0 * xs;
    const float* x1 = x0 + xs;
    for (int k = 0; k < K; ++k) {
        float4 w = *(const float4*)&W[(size_t)k*256 + c4];
        float xa = x0[k], xb = x1[k];
        a0.x = fmaf(w.x, xa, a0.x); a0.y = fmaf(w.y, xa, a0.y);
        a0.z = fmaf(w.z, xa, a0.z); a0.w = fmaf(w.w, xa, a0.w);
        a1.x = fmaf(w.x, xb, a1.x); a1.y = fmaf(w.y, xb, a1.y);
        a1.z = fmaf(w.z, xb, a1.z); a1.w = fmaf(w.w, xb, a1.w);
    }
    if (relu) {
        a0.x=fmaxf(a0.x,0.f); a0.y=fmaxf(a0.y,0.f); a0.z=fmaxf(a0.z,0.f); a0.w=fmaxf(a0.w,0.f);
        a1.x=fmaxf(a1.x,0.f); a1.y=fmaxf(a1.y,0.f); a1.z=fmaxf(a1.z,0.f); a1.w=fmaxf(a1.w,0.f);
    }
    *(float4*)&y[r0*256 + c4] = a0;
    *(float4*)&y[(r0+1)*256 + c4] = a1;
}

__device__ __forceinline__ void layer_n256_r4(
    const float* __restrict__ W, const float* __restrict__ bias, int K,
    const float* __restrict__ x, int xs, float* __restrict__ y, int relu,
    const float* __restrict__ mask, int t)
{
    const int c4 = (t & 63) * 4;
    const int r = t >> 6;
    float4 a = bias ? *(const float4*)&bias[c4] : make_float4(0.f,0.f,0.f,0.f);
    const float* xr = x + r * xs;
    for (int k = 0; k < K; ++k) {
        float4 w = *(const float4*)&W[(size_t)k*256 + c4];
        float xa = xr[k];
        a.x = fmaf(w.x, xa, a.x); a.y = fmaf(w.y, xa, a.y);
        a.z = fmaf(w.z, xa, a.z); a.w = fmaf(w.w, xa, a.w);
    }
    if (relu) {
        a.x=fmaxf(a.x,0.f); a.y=fmaxf(a.y,0.f); a.z=fmaxf(a.z,0.f); a.w=fmaxf(a.w,0.f);
    }
    if (mask) {
        float4 m = *(const float4*)&mask[r*256 + c4];
        a.x = (m.x > 0.f) ? a.x : 0.f; a.y = (m.y > 0.f) ? a.y : 0.f;
        a.z = (m.z > 0.f) ? a.z : 0.f; a.w = (m.w > 0.f) ? a.w : 0.f;
    }
    *(float4*)&y[r*256 + c4] = a;
}

__device__ __forceinline__ void layer_n128(
    const float* __restrict__ W, const float* __restrict__ bias, int K,
    const float* __restrict__ x, int xs, float* __restrict__ y, int ys, int relu,
    int rows, int t)
{
    const int c4 = (t & 31) * 4;
    int r = t >> 5; if (rows == 4) r &= 3;
    float4 a = bias ? *(const float4*)&bias[c4] : make_float4(0.f,0.f,0.f,0.f);
    const float* xr = x + r * xs;
    for (int k = 0; k < K; ++k) {
        float4 w = *(const float4*)&W[(size_t)k*128 + c4];
        float xa = xr[k];
        a.x = fmaf(w.x, xa, a.x); a.y = fmaf(w.y, xa, a.y);
        a.z = fmaf(w.z, xa, a.z); a.w = fmaf(w.w, xa, a.w);
    }
    if (relu) {
        a.x=fmaxf(a.x,0.f); a.y=fmaxf(a.y,0.f); a.z=fmaxf(a.z,0.f); a.w=fmaxf(a.w,0.f);
    }
    *(float4*)&y[r*ys + c4] = a;
}

__device__ __forceinline__ void layer_n128_dual(
    const float* __restrict__ W,
    const float* __restrict__ xA, const float* __restrict__ xB,
    float* __restrict__ y, int rows, int t)
{
    const int c4 = (t & 31) * 4;
    int r = t >> 5; if (rows == 4) r &= 3;
    float4 a = make_float4(0.f,0.f,0.f,0.f);
    const float* xa_ = xA + r * 128;
    const float* xb_ = xB + r * 128;
    for (int k = 0; k < 128; ++k) {
        float4 w = *(const float4*)&W[(size_t)k*128 + c4];
        float v = xa_[k];
        a.x = fmaf(w.x, v, a.x); a.y = fmaf(w.y, v, a.y);
        a.z = fmaf(w.z, v, a.z); a.w = fmaf(w.w, v, a.w);
    }
    for (int k = 0; k < 128; ++k) {
        float4 w = *(const float4*)&W[(size_t)(128+k)*128 + c4];
        float v = xb_[k];
        a.x = fmaf(w.x, v, a.x); a.y = fmaf(w.y, v, a.y);
        a.z = fmaf(w.z, v, a.z); a.w = fmaf(w.w, v, a.w);
    }
    *(float4*)&y[r*128 + c4] = a;
}

// ============ fused retrieve PAIR (generative+relational), 256 blocks, full GPU ======
__global__ __launch_bounds__(256) void fused_retrieve2_kernel(
    const float* __restrict__ A1a, int ld1a, const float* __restrict__ A2a, int ld2a,
    float* __restrict__ outa,
    const float* __restrict__ A1b, int ld1b, const float* __restrict__ A2b, int ld2b,
    float* __restrict__ outb,
    const float* __restrict__ qw,
    const float* __restrict__ mW1, const float* __restrict__ mb1,
    const float* __restrict__ mW2, const float* __restrict__ mb2,
    const float* __restrict__ mW3, const float* __restrict__ mb3,
    const float* __restrict__ oW1, const float* __restrict__ ob1,
    const float* __restrict__ oW2, const float* __restrict__ ob2,
    const float* __restrict__ oW3, const float* __restrict__ ob3)
{
    __shared__ float bufA[8*128], bufB[8*128], ping[8*256], pong[8*256];
    const int t = threadIdx.x;
    const bool second = blockIdx.x >= 128;
    const int row0 = (blockIdx.x & 127) * 8;
    const float* A1 = second ? A1b : A1a;  const int ld1 = second ? ld1b : ld1a;
    const float* A2 = second ? A2b : A2a;  const int ld2 = second ? ld2b : ld2a;
    float* outB = second ? outb : outa;

    stage_rows(bufA, A1, ld1, row0, 8, t);
    stage_rows(bufB, A2, ld2, row0, 8, t);
    __syncthreads();
    layer_n128_dual(qw, bufA, bufB, ping, 8, t);
    __syncthreads();
    layer_n256_r8(mW1, mb1, 128, ping, 128, pong, 1, t);
    __syncthreads();
    layer_n256_r8(mW2, mb2, 256, pong, 256, ping, 1, t);
    __syncthreads();
    layer_n128(mW3, mb3, 256, ping, 256, pong, 128, 0, 8, t);
    __syncthreads();
    layer_n256_r8(oW1, ob1, 128, pong, 128, ping, 1, t);
    __syncthreads();
    layer_n256_r8(oW2, ob2, 256, ping, 256, pong, 1, t);
    __syncthreads();
    layer_n256_r8(oW3, ob3, 256, pong, 256, ping, 0, t);
    __syncthreads();
    #pragma unroll
    for (int e = t; e < 512; e += 256) {
        int r = e >> 6, c = (e & 63) * 4;
        *(float4*)&outB[(size_t)(row0+r)*256 + c] = *(const float4*)&ping[r*256 + c];
    }
}

// ============ fused retrieve, 4 rows/block (256 blocks) for dependent calls ======
__global__ __launch_bounds__(256) void fused_retrieve4_kernel(
    const float* __restrict__ A1, int ld1,
    const float* __restrict__ A2, int ld2,
    const float* __restrict__ qw,
    const float* __restrict__ mW1, const float* __restrict__ mb1,
    const float* __restrict__ mW2, const float* __restrict__ mb2,
    const float* __restrict__ mW3, const float* __restrict__ mb3,
    const float* __restrict__ oW1, const float* __restrict__ ob1,
    const float* __restrict__ oW2, const float* __restrict__ ob2,
    const float* __restrict__ oW3, const float* __restrict__ ob3,
    float* __restrict__ outB)
{
    __shared__ float bufA[4*128], bufB[4*128], ping[4*256], pong[4*256];
    const int t = threadIdx.x;
    const int row0 = blockIdx.x * 4;

    stage_rows(bufA, A1, ld1, row0, 4, t);
    stage_rows(bufB, A2, ld2, row0, 4, t);
    __syncthreads();
    layer_n128_dual(qw, bufA, bufB, ping, 4, t);
    __syncthreads();
    layer_n256_r4(mW1, mb1, 128, ping, 128, pong, 1, nullptr, t);
    __syncthreads();
    layer_n256_r4(mW2, mb2, 256, pong, 256, ping, 1, nullptr, t);
    __syncthreads();
    layer_n128(mW3, mb3, 256, ping, 256, pong, 128, 0, 4, t);
    __syncthreads();
    layer_n256_r4(oW1, ob1, 128, pong, 128, ping, 1, nullptr, t);
    __syncthreads();
    layer_n256_r4(oW2, ob2, 256, ping, 256, pong, 1, nullptr, t);
    __syncthreads();
    layer_n256_r4(oW3, ob3, 256, pong, 256, ping, 0, nullptr, t);
    __syncthreads();
    {
        int r = t >> 6, c = (t & 63) * 4;
        *(float4*)&outB[(size_t)(row0+r)*256 + c] = *(const float4*)&ping[r*256 + c];
    }
}

// ================= fused svar: spre build + 3 layers -> pvar (1024x128) =================
__global__ __launch_bounds__(256) void fused_svar_kernel(
    const float* __restrict__ out3,
    const float* __restrict__ out1,
    const float* __restrict__ encoded,
    const float* __restrict__ sW1, const float* __restrict__ sb1,
    const float* __restrict__ sW2, const float* __restrict__ sb2,
    const float* __restrict__ sW3, const float* __restrict__ sb3,
    float* __restrict__ pvar)
{
    __shared__ float bufA[8*128], bufB[8*128], sse[8], ping[8*256], pong[8*256];
    const int t = threadIdx.x;
    const int row0 = blockIdx.x * 8;
    const int r = t >> 5, k4 = (t & 31) * 4;

    {
        float4 cs = *(const float4*)&out3[(size_t)(row0+r)*256 + k4];
        float4 ds = *(const float4*)&out1[(size_t)(row0+r)*256 + k4];
        *(float4*)&bufA[r*128 + k4] = cs;
        *(float4*)&bufB[r*128 + k4] = ds;
        float4 ce = *(const float4*)&out3[(size_t)(row0+r)*256 + 128 + k4];
        float4 en = *(const float4*)&encoded[(size_t)(row0+r)*128 + k4];
        float dx = ce.x-en.x, dy = ce.y-en.y, dz = ce.z-en.z, dw = ce.w-en.w;
        float ss = dx*dx + dy*dy + dz*dz + dw*dw;
        ss += __shfl_xor(ss, 16); ss += __shfl_xor(ss, 8); ss += __shfl_xor(ss, 4);
        ss += __shfl_xor(ss, 2);  ss += __shfl_xor(ss, 1);
        if ((t & 31) == 0) sse[r] = ss;
    }
    __syncthreads();
    {
        const int c4 = (t & 63) * 4;
        const int r0 = (t >> 6) * 2;
        float4 a0 = *(const float4*)&sb1[c4];
        float4 a1 = a0;
        for (int k = 0; k < 128; ++k) {
            float4 w = *(const float4*)&sW1[(size_t)k*256 + c4];
            float xa = bufA[r0*128 + k], xb = bufA[(r0+1)*128 + k];
            a0.x=fmaf(w.x,xa,a0.x); a0.y=fmaf(w.y,xa,a0.y); a0.z=fmaf(w.z,xa,a0.z); a0.w=fmaf(w.w,xa,a0.w);
            a1.x=fmaf(w.x,xb,a1.x); a1.y=fmaf(w.y,xb,a1.y); a1.z=fmaf(w.z,xb,a1.z); a1.w=fmaf(w.w,xb,a1.w);
        }
        for (int k = 0; k < 128; ++k) {
            float4 w = *(const float4*)&sW1[(size_t)(128+k)*256 + c4];
            float xa = bufB[r0*128 + k], xb = bufB[(r0+1)*128 + k];
            a0.x=fmaf(w.x,xa,a0.x); a0.y=fmaf(w.y,xa,a0.y); a0.z=fmaf(w.z,xa,a0.z); a0.w=fmaf(w.w,xa,a0.w);
            a1.x=fmaf(w.x,xb,a1.x); a1.y=fmaf(w.y,xb,a1.y); a1.z=fmaf(w.z,xb,a1.z); a1.w=fmaf(w.w,xb,a1.w);
        }
        {
            float4 w = *(const float4*)&sW1[(size_t)256*256 + c4];
            float xa = sse[r0], xb = sse[r0+1];
            a0.x=fmaf(w.x,xa,a0.x); a0.y=fmaf(w.y,xa,a0.y); a0.z=fmaf(w.z,xa,a0.z); a0.w=fmaf(w.w,xa,a0.w);
            a1.x=fmaf(w.x,xb,a1.x); a1.y=fmaf(w.y,xb,a1.y); a1.z=fmaf(w.z,xb,a1.z); a1.w=fmaf(w.w,xb,a1.w);
        }
        a0.x=fmaxf(a0.x,0.f); a0.y=fmaxf(a0.y,0.f); a0.z=fmaxf(a0.z,0.f); a0.w=fmaxf(a0.w,0.f);
        a1.x=fmaxf(a1.x,0.f); a1.y=fmaxf(a1.y,0.f); a1.z=fmaxf(a1.z,0.f); a1.w=fmaxf(a1.w,0.f);
        *(float4*)&ping[r0*256 + c4] = a0;
        *(float4*)&ping[(r0+1)*256 + c4] = a1;
    }
    __syncthreads();
    layer_n256_r8(sW2, sb2, 256, ping, 256, pong, 1, t);
    __syncthreads();
    layer_n128(sW3, sb3, 256, pong, 256, ping, 128, 0, 8, t);
    __syncthreads();
    {
        int rr = t >> 5, c = (t & 31) * 4;
        *(float4*)&pvar[(size_t)(row0+rr)*128 + c] = *(const float4*)&ping[rr*128 + c];
    }
}

// ================= fused grad: keys/vals proj + meta fwd/bwd + grad writes =================
__global__ __launch_bounds__(256) void fused_grad_kernel(
    const float* __restrict__ A1,       // out4 (final_s in cols 0..127), ld 256
    const float* __restrict__ encoded,  // ld 128
    const float* __restrict__ k_w, const float* __restrict__ v_w,
    const float* __restrict__ mW1, const float* __restrict__ mb1,
    const float* __restrict__ mW2, const float* __restrict__ mb2,
    const float* __restrict__ mW3, const float* __restrict__ mb3,
    const float* __restrict__ T2,
    const float* __restrict__ T3,
    float* __restrict__ out)
{
    __shared__ float bufA[4*128], bufB[4*128], ks[4*128], vs[4*128];
    __shared__ float h1[4*256], h2[4*256], dob[4*128], dh2[4*256], dh1[4*256];
    const int t = threadIdx.x;
    const int row0 = blockIdx.x * 4;

    stage_rows(bufA, A1, 256, row0, 4, t);
    stage_rows(bufB, encoded, 128, row0, 4, t);
    __syncthreads();
    layer_n128_dual(k_w, bufA, bufB, ks, 4, t);
    layer_n128_dual(v_w, bufA, bufB, vs, 4, t);
    __syncthreads();
    layer_n256_r4(mW1, mb1, 128, ks, 128, h1, 1, nullptr, t);
    __syncthreads();
    layer_n256_r4(mW2, mb2, 256, h1, 256, h2, 1, nullptr, t);
    __syncthreads();
    layer_n128(mW3, mb3, 256, h2, 256, dob, 128, 0, 4, t);
    __syncthreads();
    for (int e = t; e < 512; e += 256)
        dob[e] = (dob[e] - vs[e]) * 0.015625f;               // 2/128
    __syncthreads();
    layer_n256_r4(T3, nullptr, 128, dob, 128, dh2, 0, h2, t);
    __syncthreads();
    layer_n256_r4(T2, nullptr, 256, dh2, 256, dh1, 0, h1, t);
    __syncthreads();

    #pragma unroll
    for (int r = 0; r < 4; ++r) {
        const size_t row = row0 + r;
        {   // W1 grad: 128 x 256, float4 stores
            const int c4 = (t & 63) * 4;
            const int i0 = (t >> 6) * 32;
            const float4 dv = *(const float4*)&dh1[r*256 + c4];
            float* p = out + OFF_W1 + row*32768;
            for (int i = i0; i < i0 + 32; ++i) {
                float kv = ks[r*128 + i];
                float4 o; o.x = kv*dv.x; o.y = kv*dv.y; o.z = kv*dv.z; o.w = kv*dv.w;
                *(float4*)&p[(size_t)i*256 + c4] = o;
            }
            out[OFF_B1 + row*256 + t] = dh1[r*256 + t];
        }
        {   // W2 grad: 256 x 256
            const int c4 = (t & 63) * 4;
            const int i0 = (t >> 6) * 64;
            const float4 dv = *(const float4*)&dh2[r*256 + c4];
            float* p = out + OFF_W2 + row*65536;
            for (int i = i0; i < i0 + 64; ++i) {
                float hv = h1[r*256 + i];
                float4 o; o.x = hv*dv.x; o.y = hv*dv.y; o.z = hv*dv.z; o.w = hv*dv.w;
                *(float4*)&p[(size_t)i*256 + c4] = o;
            }
            out[OFF_B2 + row*256 + t] = dh2[r*256 + t];
        }
        {   // W3 grad: 256 x 128
            const int c4 = (t & 31) * 4;
            const int i0 = (t >> 5) * 32;
            const float4 dv = *(const float4*)&dob[r*128 + c4];
            float* p = out + OFF_W3 + row*32768;
            for (int i = i0; i < i0 + 32; ++i) {
                float hv = h2[r*256 + i];
                float4 o; o.x = hv*dv.x; o.y = hv*dv.y; o.z = hv*dv.z; o.w = hv*dv.w;
                *(float4*)&p[(size_t)i*128 + c4] = o;
            }
            if (t < 128) out[OFF_B3 + row*128 + t] = dob[r*128 + t];
        }
    }
}

// ================= misc small kernels =================
__global__ __launch_bounds__(256) void mse_kernel(
    const float* __restrict__ A, int lda,
    const float* __restrict__ Bm, int ldb,
    int N, float scale, float* __restrict__ accum)
{
    const int m = blockIdx.x;
    float s = 0.f;
    for (int jj = threadIdx.x; jj < N; jj += 256) {
        float d = A[(size_t)m*lda + jj] - Bm[(size_t)m*ldb + jj];
        s = fmaf(d, d, s);
    }
    #pragma unroll
    for (int off = 32; off > 0; off >>= 1) s += __shfl_down(s, off, 64);
    __shared__ float w[4];
    if ((threadIdx.x & 63) == 0) w[threadIdx.x >> 6] = s;
    __syncthreads();
    if (threadIdx.x == 0) atomicAdd(accum, (w[0]+w[1]+w[2]+w[3]) * scale);
}

__global__ __launch_bounds__(128) void infs_kernel(
    const float* __restrict__ out1,
    const float* __restrict__ out3,
    const float* __restrict__ pvar,
    const float* __restrict__ ratio_p,
    float* __restrict__ inf_s,
    float scale, float* __restrict__ accum)
{
    const int m = blockIdx.x, t = threadIdx.x;
    float ratio = ratio_p[0];
    float dgs = out1[(size_t)m*256 + t];
    float cs  = out3[(size_t)m*256 + t];
    float pv  = pvar[(size_t)m*128 + t];
    float delta = (cs - dgs) * ratio * pv;
    inf_s[(size_t)m*128 + t] = dgs + delta;
    float ss = delta * delta;
    #pragma unroll
    for (int off = 32; off > 0; off >>= 1) ss += __shfl_down(ss, off, 64);
    __shared__ float w2[2];
    if ((t & 63) == 0) w2[t >> 6] = ss;
    __syncthreads();
    if (t == 0) atomicAdd(accum, (w2[0] + w2[1]) * scale);
}

__global__ void total_kernel(const float* acc, float* out) {
    if (threadIdx.x == 0)
        out[0] = acc[0] + acc[1] + acc[2] + acc[3];
}

// ================= host =================
static inline void gemmF(const float* A, int lda, const float* W, int ldw, const float* bias,
                         float* C, int N, int K, int relu, hipStream_t s)
{
    dim3 g(16, (N + 63) / 64);
    gemm_kernel<<<g, 256, 0, s>>>(A, lda, W, ldw, bias, C, N, N, K, relu);
}

extern "C" void kernel_launch(void* const* d_in, const int* in_sizes, int n_in,
                              void* d_out, int out_size, void* d_ws, size_t ws_size,
                              hipStream_t stream)
{
    const float* sensory     = (const float*)d_in[0];
    const float* actions     = (const float*)d_in[1];
    const float* init_hidden = (const float*)d_in[2];
    const float* tW1 = (const float*)d_in[3];  const float* tb1 = (const float*)d_in[4];
    const float* tW2 = (const float*)d_in[5];  const float* tb2 = (const float*)d_in[6];
    const float* tW3 = (const float*)d_in[7];  const float* tb3 = (const float*)d_in[8];
    const float* enc_w = (const float*)d_in[9];  const float* enc_b = (const float*)d_in[10];
    const float* dec_w = (const float*)d_in[11]; const float* dec_b = (const float*)d_in[12];
    const float* q_w = (const float*)d_in[13];
    const float* k_w = (const float*)d_in[14];
    const float* v_w = (const float*)d_in[15];
    const float* mW1 = (const float*)d_in[16]; const float* mb1 = (const float*)d_in[17];
    const float* mW2 = (const float*)d_in[18]; const float* mb2 = (const float*)d_in[19];
    const float* mW3 = (const float*)d_in[20]; const float* mb3 = (const float*)d_in[21];
    const float* oW1 = (const float*)d_in[22]; const float* ob1 = (const float*)d_in[23];
    const float* oW2 = (const float*)d_in[24]; const float* ob2 = (const float*)d_in[25];
    const float* oW3 = (const float*)d_in[26]; const float* ob3 = (const float*)d_in[27];
    const float* sW1 = (const float*)d_in[28]; const float* sb1 = (const float*)d_in[29];
    const float* sW2 = (const float*)d_in[30]; const float* sb2 = (const float*)d_in[31];
    const float* sW3 = (const float*)d_in[32]; const float* sb3 = (const float*)d_in[33];
    const float* ratio = (const float*)d_in[34];
    float* out = (float*)d_out;

    // workspace layout (floats) — total 19,234,832 floats, identical to the proven
    // previous session's footprint. tW3T (2,097,152 = 128x16384) aliases the block of
    // buffers all first-written AFTER the trans GEMM consumes tW3T (a1 is dead after
    // the a2 GEMM, which runs before prep writes tW3T).
    float* Wsp = (float*)d_ws;
    float* acc   = Wsp;                         // 16
    float* ALIAS = Wsp + 16;                    // 2,097,152 floats total
    float* a1_buf     = ALIAS;                  // 131072  (dead before prep writes tW3T)
    float* structural = ALIAS + 131072;         // 131072  (scan writes after tW3T dead)
    float* out1 = ALIAS + 262144;               // 262144
    float* out2 = ALIAS + 524288;               // 262144
    float* out3 = ALIAS + 786432;               // 262144
    float* out4 = ALIAS + 1048576;              // 262144
    float* pvar = ALIAS + 1310720;              // 131072
    float* infs = ALIAS + 1441792;              // 131072
    float* tW3T = ALIAS;                        // full 2,097,152
    size_t off = 16 + 2097152;
    float* a2      = Wsp + off; off += 131072;
    float* encoded = Wsp + off; off += 131072;
    float* transT  = Wsp + off; off += 16777216;
    float* T2      = Wsp + off; off += 65536;
    float* T3      = Wsp + off; off += 32768;

    // PathIntegration transitions MLP (layers 1-2) BEFORE prep (a1 slot reused by tW3T)
    gemmF(actions, 32, tW1, 128, tb1, a1_buf, 128, 32, 1, stream);
    gemmF(a1_buf, 128, tW2, 128, tb2, a2, 128, 128, 1, stream);

    // prep: tW3^T (per-k 128x128 transpose -> col-major trans), T2, T3, zero acc
    prep_kernel<<<641, 256, 0, stream>>>(tW3, mW2, mW3, tW3T, T2, T3, acc);

    // encoder (linear)
    gemmF(sensory, 512, enc_w, 128, enc_b, encoded, 128, 512, 0, stream);

    // transitions layer 3: dedicated K=128 GEMM -> transT (col-major per step)
    // bias_mode=1: tb3 read through the transposed index (no tb3T table needed)
    gemm_k128_kernel<<<dim3(32, 64), 256, 0, stream>>>(a2, 128, tW3T, tb3, 1, transT, 16384);

    // scripted RNN scan (col-major T, lane-local contraction)
    scan_kernel3<<<8, 512, 0, stream>>>(transT, init_hidden, structural);

    // generative retrieve(structural,0) + relational retrieve(0,encoded) in ONE launch
    fused_retrieve2_kernel<<<256, 256, 0, stream>>>(
        structural, 128, nullptr, 0, out1,
        nullptr, 0, encoded, 128, out2,
        q_w, mW1, mb1, mW2, mb2, mW3, mb3, oW1, ob1, oW2, ob2, oW3, ob3);

    // relational loss (x2)
    mse_kernel<<<1024, 256, 0, stream>>>(out2, 256, structural, 128, 128, 2.f/131072.f, acc + 1);
    // generative pred loss: decoder GEMM + MSE fused (no deco materialization)
    gemm_k128_mse_kernel<<<dim3(32, 2), 256, 0, stream>>>(
        out1 + 128, 256, dec_w, dec_b, sensory, 512, 1.f/524288.f, acc + 0);

    // consistency: retrieve(dec_gen_s, encoded)
    fused_retrieve4_kernel<<<256, 256, 0, stream>>>(out1, 256, encoded, 128,
        q_w, mW1, mb1, mW2, mb2, mW3, mb3, oW1, ob1, oW2, ob2, oW3, ob3, out3);
    fused_svar_kernel<<<128, 256, 0, stream>>>(out3, out1, encoded,
        sW1, sb1, sW2, sb2, sW3, sb3, pvar);
    infs_kernel<<<1024, 128, 0, stream>>>(out1, out3, pvar, ratio, infs, 1.f/131072.f, acc + 2);

    // inference: retrieve(inf_s, 0)
    fused_retrieve4_kernel<<<256, 256, 0, stream>>>(infs, 128, nullptr, 0,
        q_w, mW1, mb1, mW2, mb2, mW3, mb3, oW1, ob1, oW2, ob2, oW3, ob3, out4);
    gemm_k128_mse_kernel<<<dim3(32, 2), 256, 0, stream>>>(
        out4 + 128, 256, dec_w, dec_b, sensory, 512, 1.f/524288.f, acc + 3);

    // fast-weight memory grads
    fused_grad_kernel<<<256, 256, 0, stream>>>(out4, encoded, k_w, v_w,
        mW1, mb1, mW2, mb2, mW3, mb3, T2, T3, out);

    total_kernel<<<1, 64, 0, stream>>>(acc, out);
}

// Round 4
// 1337.189 us; speedup vs baseline: 1.1467x; 1.0953x over previous
//
#include <hip/hip_runtime.h>
#include <hip/hip_bf16.h>

// ---------------- output layout constants (floats) ----------------
constexpr size_t OFF_W1 = 1;
constexpr size_t OFF_B1 = OFF_W1 + (size_t)1024*32768;
constexpr size_t OFF_W2 = OFF_B1 + (size_t)1024*256;
constexpr size_t OFF_B2 = OFF_W2 + (size_t)1024*65536;
constexpr size_t OFF_W3 = OFF_B2 + (size_t)1024*256;
constexpr size_t OFF_B3 = OFF_W3 + (size_t)1024*32768;

// ================= fused-MLP building blocks (proven) =================
__device__ __forceinline__ void stage_rows(float* buf, const float* src, int ld,
                                           int row0, int rows, int t)
{
    int r = t >> 5; if (rows == 4) r &= 3;
    const int k4 = (t & 31) * 4;
    float4 v = make_float4(0.f,0.f,0.f,0.f);
    if (src) v = *(const float4*)&src[(size_t)(row0 + r)*ld + k4];
    *(float4*)&buf[r*128 + k4] = v;
}

__device__ __forceinline__ void layer_n256_r8(
    const float* __restrict__ W, const float* __restrict__ bias, int K,
    const float* __restrict__ x, int xs, float* __restrict__ y, int relu, int t)
{
    const int c4 = (t & 63) * 4;
    const int r0 = (t >> 6) * 2;
    float4 a0 = bias ? *(const float4*)&bias[c4] : make_float4(0.f,0.f,0.f,0.f);
    float4 a1 = a0;
    const float* x0 = x + r0 * xs;
    const float* x1 = x0 + xs;
    for (int k = 0; k < K; ++k) {
        float4 w = *(const float4*)&W[(size_t)k*256 + c4];
        float xa = x0[k], xb = x1[k];
        a0.x = fmaf(w.x, xa, a0.x); a0.y = fmaf(w.y, xa, a0.y);
        a0.z = fmaf(w.z, xa, a0.z); a0.w = fmaf(w.w, xa, a0.w);
        a1.x = fmaf(w.x, xb, a1.x); a1.y = fmaf(w.y, xb, a1.y);
        a1.z = fmaf(w.z, xb, a1.z); a1.w = fmaf(w.w, xb, a1.w);
    }
    if (relu) {
        a0.x=fmaxf(a0.x,0.f); a0.y=fmaxf(a0.y,0.f); a0.z=fmaxf(a0.z,0.f); a0.w=fmaxf(a0.w,0.f);
        a1.x=fmaxf(a1.x,0.f); a1.y=fmaxf(a1.y,0.f); a1.z=fmaxf(a1.z,0.f); a1.w=fmaxf(a1.w,0.f);
    }
    *(float4*)&y[r0*256 + c4] = a0;
    *(float4*)&y[(r0+1)*256 + c4] = a1;
}

__device__ __forceinline__ void layer_n256_r4(
    const float* __restrict__ W, const float* __restrict__ bias, int K,
    const float* __restrict__ x, int xs, float* __restrict__ y, int relu,
    const float* __restrict__ mask, int t)
{
    const int c4 = (t & 63) * 4;
    const int r = t >> 6;
    float4 a = bias ? *(const float4*)&bias[c4] : make_float4(0.f,0.f,0.f,0.f);
    const float* xr = x + r * xs;
    for (int k = 0; k < K; ++k) {
        float4 w = *(const float4*)&W[(size_t)k*256 + c4];
        float xa = xr[k];
        a.x = fmaf(w.x, xa, a.x); a.y = fmaf(w.y, xa, a.y);
        a.z = fmaf(w.z, xa, a.z); a.w = fmaf(w.w, xa, a.w);
    }
    if (relu) {
        a.x=fmaxf(a.x,0.f); a.y=fmaxf(a.y,0.f); a.z=fmaxf(a.z,0.f); a.w=fmaxf(a.w,0.f);
    }
    if (mask) {
        float4 m = *(const float4*)&mask[r*256 + c4];
        a.x = (m.x > 0.f) ? a.x : 0.f; a.y = (m.y > 0.f) ? a.y : 0.f;
        a.z = (m.z > 0.f) ? a.z : 0.f; a.w = (m.w > 0.f) ? a.w : 0.f;
    }
    *(float4*)&y[r*256 + c4] = a;
}

__device__ __forceinline__ void layer_n128(
    const float* __restrict__ W, const float* __restrict__ bias, int K,
    const float* __restrict__ x, int xs, float* __restrict__ y, int ys, int relu,
    int rows, int t)
{
    const int c4 = (t & 31) * 4;
    int r = t >> 5; if (rows == 4) r &= 3;
    float4 a = bias ? *(const float4*)&bias[c4] : make_float4(0.f,0.f,0.f,0.f);
    const float* xr = x + r * xs;
    for (int k = 0; k < K; ++k) {
        float4 w = *(const float4*)&W[(size_t)k*128 + c4];
        float xa = xr[k];
        a.x = fmaf(w.x, xa, a.x); a.y = fmaf(w.y, xa, a.y);
        a.z = fmaf(w.z, xa, a.z); a.w = fmaf(w.w, xa, a.w);
    }
    if (relu) {
        a.x=fmaxf(a.x,0.f); a.y=fmaxf(a.y,0.f); a.z=fmaxf(a.z,0.f); a.w=fmaxf(a.w,0.f);
    }
    *(float4*)&y[r*ys + c4] = a;
}

__device__ __forceinline__ void layer_n128_dual(
    const float* __restrict__ W,
    const float* __restrict__ xA, const float* __restrict__ xB,
    float* __restrict__ y, int rows, int t)
{
    const int c4 = (t & 31) * 4;
    int r = t >> 5; if (rows == 4) r &= 3;
    float4 a = make_float4(0.f,0.f,0.f,0.f);
    const float* xa_ = xA + r * 128;
    const float* xb_ = xB + r * 128;
    for (int k = 0; k < 128; ++k) {
        float4 w = *(const float4*)&W[(size_t)k*128 + c4];
        float v = xa_[k];
        a.x = fmaf(w.x, v, a.x); a.y = fmaf(w.y, v, a.y);
        a.z = fmaf(w.z, v, a.z); a.w = fmaf(w.w, v, a.w);
    }
    for (int k = 0; k < 128; ++k) {
        float4 w = *(const float4*)&W[(size_t)(128+k)*128 + c4];
        float v = xb_[k];
        a.x = fmaf(w.x, v, a.x); a.y = fmaf(w.y, v, a.y);
        a.z = fmaf(w.z, v, a.z); a.w = fmaf(w.w, v, a.w);
    }
    *(float4*)&y[r*128 + c4] = a;
}

// ================= dedicated K=128 GEMM compute (proven) ========
__device__ __forceinline__ void gemm_k128_compute(
    const float* __restrict__ A, int lda, const float* __restrict__ W,
    const float* __restrict__ bias, int bias_mode, int N, int m0, int n0, int t,
    float* __restrict__ As, float4* __restrict__ acc)
{
    for (int l = t; l < 4096; l += 256) {
        int r = l >> 7, k = l & 127;
        As[k*36 + r] = A[(size_t)(m0 + r)*lda + k];
    }
    __syncthreads();
    const int c4 = (t & 63) * 4;
    const int r0 = (t >> 6) * 8;
    float4 bv;
    if (bias_mode == 0) {
        bv = *(const float4*)&bias[n0 + c4];
    } else {
        const int n = n0 + c4;
        const int j = n >> 7, i = n & 127;
        bv.x = bias[(size_t)(i+0)*128 + j];
        bv.y = bias[(size_t)(i+1)*128 + j];
        bv.z = bias[(size_t)(i+2)*128 + j];
        bv.w = bias[(size_t)(i+3)*128 + j];
    }
    #pragma unroll
    for (int i = 0; i < 8; ++i) acc[i] = bv;
    const float* Wp = W + (size_t)n0 + c4;
    #pragma unroll 4
    for (int k = 0; k < 128; ++k) {
        float4 w = *(const float4*)&Wp[(size_t)k*N];
        float a[8];
        *(float4*)&a[0] = *(const float4*)&As[k*36 + r0];
        *(float4*)&a[4] = *(const float4*)&As[k*36 + r0 + 4];
        #pragma unroll
        for (int i = 0; i < 8; ++i) {
            acc[i].x = fmaf(w.x, a[i], acc[i].x);
            acc[i].y = fmaf(w.y, a[i], acc[i].y);
            acc[i].z = fmaf(w.z, a[i], acc[i].z);
            acc[i].w = fmaf(w.w, a[i], acc[i].w);
        }
    }
}

__global__ __launch_bounds__(256) void gemm_k128_kernel(
    const float* __restrict__ A, int lda, const float* __restrict__ W,
    const float* __restrict__ bias, int bias_mode, float* __restrict__ C, int N)
{
    __shared__ float As[128*36];
    float4 acc[8];
    const int t = threadIdx.x;
    const int m0 = blockIdx.x * 32, n0 = blockIdx.y * 256;
    gemm_k128_compute(A, lda, W, bias, bias_mode, N, m0, n0, t, As, acc);
    const int c4 = (t & 63) * 4;
    const int r0 = (t >> 6) * 8;
    #pragma unroll
    for (int i = 0; i < 8; ++i)
        *(float4*)&C[(size_t)(m0 + r0 + i)*N + n0 + c4] = acc[i];
}

// reduce helper: block-sum of s (256 threads), result via atomicAdd(accum, total*scale)
__device__ __forceinline__ void block_mse_commit(float s, float scale,
                                                 float* __restrict__ accum,
                                                 float* __restrict__ red, int t)
{
    #pragma unroll
    for (int off = 32; off > 0; off >>= 1) s += __shfl_down(s, off, 64);
    if ((t & 63) == 0) red[t >> 6] = s;
    __syncthreads();
    if (t == 0) atomicAdd(accum, (red[0]+red[1]+red[2]+red[3]) * scale);
}

// ================= launch 1: prep (tW3^T, T2, T3, acc zero, a1->a2 MLP, encoder) ====
// blocks 0..255: tW3 tiles; 256..511: T2; 512..639: T3; 640: zero;
// 641..768: a12 MLP (8 rows each); 769..800: encoder GEMM (flattened 16x2)
__global__ __launch_bounds__(256) void prep_kernel(
    const float* __restrict__ tW3,
    const float* __restrict__ mW2, const float* __restrict__ mW3,
    const float* __restrict__ actions,
    const float* __restrict__ tW1, const float* __restrict__ tb1,
    const float* __restrict__ tW2, const float* __restrict__ tb2,
    const float* __restrict__ sensory,
    const float* __restrict__ enc_w, const float* __restrict__ enc_b,
    float* __restrict__ tW3T, float* __restrict__ T2, float* __restrict__ T3,
    float* __restrict__ acc, float* __restrict__ a2, float* __restrict__ encoded)
{
    __shared__ float smem[64*129];
    const int t = threadIdx.x;
    const int bid = blockIdx.x;
    if (bid < 256) {
        const int k = bid >> 1, i0 = (bid & 1) * 64;
        const size_t base = (size_t)k << 14;
        for (int l = t; l < 8192; l += 256) {
            int ii = l >> 7, jj = l & 127;
            smem[ii*129 + jj] = tW3[base + (size_t)(i0+ii)*128 + jj];
        }
        __syncthreads();
        for (int l = t; l < 8192; l += 256) {
            int jj = l >> 6, ii = l & 63;
            tW3T[base + (size_t)jj*128 + i0 + ii] = smem[ii*129 + jj];
        }
    } else if (bid < 512) {
        const int c = bid - 256;
        T2[(size_t)c*256 + t] = mW2[(size_t)t*256 + c];
    } else if (bid < 640) {
        const int c = bid - 512;
        T3[(size_t)c*256 + t] = mW3[(size_t)t*128 + c];
    } else if (bid == 640) {
        if (t < 16) acc[t] = 0.f;
    } else if (bid < 769) {
        // a12: actions(8x32) -> relu@tW1 -> relu@tW2 -> a2 rows
        float* bufAct = smem;            // 256
        float* ping   = smem + 256;      // 1024
        float* pong   = smem + 1280;     // 1024
        const int row0 = (bid - 641) * 8;
        if (t < 64) {
            int r = t >> 3, c4 = (t & 7) * 4;
            *(float4*)&bufAct[r*32 + c4] =
                *(const float4*)&actions[(size_t)(row0 + r)*32 + c4];
        }
        __syncthreads();
        layer_n128(tW1, tb1, 32, bufAct, 32, ping, 128, 1, 8, t);
        __syncthreads();
        layer_n128(tW2, tb2, 128, ping, 128, pong, 128, 1, 8, t);
        __syncthreads();
        {
            int r = t >> 5, c4 = (t & 31) * 4;
            *(float4*)&a2[(size_t)(row0 + r)*128 + c4] = *(const float4*)&pong[r*128 + c4];
        }
    } else {
        // encoder: sensory(1024x512) @ enc_w(512x128) + enc_b -> encoded
        const int q = bid - 769;              // 0..31
        const int m0 = (q & 15) * 64, n0 = (q >> 4) * 64;
        float (*As)[65] = (float(*)[65])smem;
        float (*Ws)[65] = (float(*)[65])(smem + 16*65);
        const int tx = t & 15, ty = t >> 4;
        float a4[4][4] = {};
        for (int k0 = 0; k0 < 512; k0 += 16) {
            for (int l = t; l < 1024; l += 256) {
                int mm = l >> 4, kk = l & 15;
                As[kk][mm] = sensory[(size_t)(m0+mm)*512 + k0 + kk];
            }
            for (int l = t; l < 1024; l += 256) {
                int kk = l >> 6, nn = l & 63;
                Ws[kk][nn] = enc_w[(size_t)(k0+kk)*128 + n0 + nn];
            }
            __syncthreads();
            #pragma unroll
            for (int kk = 0; kk < 16; ++kk) {
                float a[4], b[4];
                #pragma unroll
                for (int i=0;i<4;i++) a[i] = As[kk][ty*4+i];
                #pragma unroll
                for (int j=0;j<4;j++) b[j] = Ws[kk][tx*4+j];
                #pragma unroll
                for (int i=0;i<4;i++)
                    #pragma unroll
                    for (int j=0;j<4;j++)
                        a4[i][j] = fmaf(a[i], b[j], a4[i][j]);
            }
            __syncthreads();
        }
        #pragma unroll
        for (int i=0;i<4;i++){
            int gm = m0 + ty*4 + i;
            #pragma unroll
            for (int j=0;j<4;j++){
                int gn = n0 + tx*4 + j;
                encoded[(size_t)gm*128 + gn] = a4[i][j] + enc_b[gn];
            }
        }
    }
}

// ================= launch 3: scan (blocks 0..7) + relational retrieve (8..135) ======
__global__ __launch_bounds__(512) void scanrel_kernel(
    const float* __restrict__ transT,
    const float* __restrict__ init_hidden,
    float* __restrict__ structural,
    const float* __restrict__ encoded,
    const float* __restrict__ qw,
    const float* __restrict__ mW1, const float* __restrict__ mb1,
    const float* __restrict__ mW2, const float* __restrict__ mb2,
    const float* __restrict__ mW3, const float* __restrict__ mb3,
    const float* __restrict__ oW1, const float* __restrict__ ob1,
    const float* __restrict__ oW2, const float* __restrict__ ob2,
    const float* __restrict__ oW3, const float* __restrict__ ob3,
    float* __restrict__ out2)
{
    __shared__ float smem[5120];
    const int tid = threadIdx.x;
    if (blockIdx.x < 8) {
        // ---- scan: col-major trans, lane-local i-contraction ----
        float* h  = smem;        // 128
        float* ws = smem + 128;  // 8
        const int b = blockIdx.x;
        const int j = tid >> 2, p = tid & 3;
        const int i0 = p * 32;

        if (tid < 32) {
            float4 v = *(const float4*)&init_hidden[tid*4];
            float ss = v.x*v.x + v.y*v.y + v.z*v.z + v.w*v.w;
            ss += __shfl_xor(ss, 16); ss += __shfl_xor(ss, 8); ss += __shfl_xor(ss, 4);
            ss += __shfl_xor(ss, 2);  ss += __shfl_xor(ss, 1);
            float inv = 1.f / fmaxf(sqrtf(ss), 1e-12f);
            v.x *= inv; v.y *= inv; v.z *= inv; v.w *= inv;
            *(float4*)&h[tid*4] = v;
        }
        __syncthreads();

        const size_t bbase = ((size_t)b) << 21;
        const int lane_off = j*128 + i0;
        float4 cur[8], nxt[8];
        {
            const float* T0 = transT + bbase + lane_off;
            #pragma unroll
            for (int r = 0; r < 8; ++r) cur[r] = *(const float4*)&T0[r*4];
        }
        for (int t = 0; t < 128; ++t) {
            const int tn = (t < 127) ? t + 1 : 127;
            const float* Tn = transT + bbase + ((size_t)tn << 14) + lane_off;
            #pragma unroll
            for (int r = 0; r < 8; ++r) nxt[r] = *(const float4*)&Tn[r*4];

            float4 a = make_float4(0.f, 0.f, 0.f, 0.f);
            #pragma unroll
            for (int r = 0; r < 8; ++r) {
                float4 hv = *(const float4*)&h[i0 + r*4];
                a.x = fmaf(hv.x, cur[r].x, a.x);
                a.y = fmaf(hv.y, cur[r].y, a.y);
                a.z = fmaf(hv.z, cur[r].z, a.z);
                a.w = fmaf(hv.w, cur[r].w, a.w);
            }
            float s = (a.x + a.y) + (a.z + a.w);
            s += __shfl_xor(s, 1);
            s += __shfl_xor(s, 2);
            float v = fmaxf(s, 0.f);
            float q = v * v;
            q += __shfl_xor(q, 4);  q += __shfl_xor(q, 8);
            q += __shfl_xor(q, 16); q += __shfl_xor(q, 32);
            if ((tid & 63) == 0) ws[tid >> 6] = q;
            __syncthreads();
            float ss = ((ws[0]+ws[1]) + (ws[2]+ws[3])) + ((ws[4]+ws[5]) + (ws[6]+ws[7]));
            float inv = 1.f / fmaxf(sqrtf(ss), 1e-12f);
            float hv = v * inv;
            __syncthreads();
            if (p == 0) h[j] = hv;
            else if (p == 1) structural[(((size_t)(b*128 + t)) << 7) + j] = hv;
            __syncthreads();
            #pragma unroll
            for (int r = 0; r < 8; ++r) cur[r] = nxt[r];
        }
    } else {
        // ---- relational retrieve(0, encoded), 8 rows; threads 0..255 active ----
        float* bufB = smem;           // 1024
        float* ping = smem + 1024;    // 2048
        float* pong = smem + 3072;    // 2048
        const int row0 = (blockIdx.x - 8) * 8;
        const bool act = (tid < 256);
        const int t = tid;
        if (act) stage_rows(bufB, encoded, 128, row0, 8, t);
        __syncthreads();
        if (act) layer_n128(qw + (size_t)128*128, nullptr, 128, bufB, 128, ping, 128, 0, 8, t);
        __syncthreads();
        if (act) layer_n256_r8(mW1, mb1, 128, ping, 128, pong, 1, t);
        __syncthreads();
        if (act) layer_n256_r8(mW2, mb2, 256, pong, 256, ping, 1, t);
        __syncthreads();
        if (act) layer_n128(mW3, mb3, 256, ping, 256, pong, 128, 0, 8, t);
        __syncthreads();
        if (act) layer_n256_r8(oW1, ob1, 128, pong, 128, ping, 1, t);
        __syncthreads();
        if (act) layer_n256_r8(oW2, ob2, 256, ping, 256, pong, 1, t);
        __syncthreads();
        if (act) layer_n256_r8(oW3, ob3, 256, pong, 256, ping, 0, t);
        __syncthreads();
        if (act) {
            for (int e = t; e < 512; e += 256) {
                int r = e >> 6, c = (e & 63) * 4;
                *(float4*)&out2[(size_t)(row0+r)*256 + c] = *(const float4*)&ping[r*256 + c];
            }
        }
    }
}

// ====== launch 4: generative retrieve (blocks 0..127) + relational mse (128..1151) ==
__global__ __launch_bounds__(256) void genmse_kernel(
    const float* __restrict__ structural,
    const float* __restrict__ qw,
    const float* __restrict__ mW1, const float* __restrict__ mb1,
    const float* __restrict__ mW2, const float* __restrict__ mb2,
    const float* __restrict__ mW3, const float* __restrict__ mb3,
    const float* __restrict__ oW1, const float* __restrict__ ob1,
    const float* __restrict__ oW2, const float* __restrict__ ob2,
    const float* __restrict__ oW3, const float* __restrict__ ob3,
    float* __restrict__ out1,
    const float* __restrict__ out2,
    float* __restrict__ acc)
{
    __shared__ float smem[5120];
    const int t = threadIdx.x;
    if (blockIdx.x < 128) {
        float* bufA = smem;           // 1024
        float* ping = smem + 1024;    // 2048
        float* pong = smem + 3072;    // 2048
        const int row0 = blockIdx.x * 8;
        stage_rows(bufA, structural, 128, row0, 8, t);
        __syncthreads();
        layer_n128(qw, nullptr, 128, bufA, 128, ping, 128, 0, 8, t);
        __syncthreads();
        layer_n256_r8(mW1, mb1, 128, ping, 128, pong, 1, t);
        __syncthreads();
        layer_n256_r8(mW2, mb2, 256, pong, 256, ping, 1, t);
        __syncthreads();
        layer_n128(mW3, mb3, 256, ping, 256, pong, 128, 0, 8, t);
        __syncthreads();
        layer_n256_r8(oW1, ob1, 128, pong, 128, ping, 1, t);
        __syncthreads();
        layer_n256_r8(oW2, ob2, 256, ping, 256, pong, 1, t);
        __syncthreads();
        layer_n256_r8(oW3, ob3, 256, pong, 256, ping, 0, t);
        __syncthreads();
        for (int e = t; e < 512; e += 256) {
            int r = e >> 6, c = (e & 63) * 4;
            *(float4*)&out1[(size_t)(row0+r)*256 + c] = *(const float4*)&ping[r*256 + c];
        }
    } else {
        // relational loss: mse(out2[:, :128], structural) * 2
        const int m = blockIdx.x - 128;
        float s = 0.f;
        for (int jj = t; jj < 128; jj += 256) {
            float d = out2[(size_t)m*256 + jj] - structural[(size_t)m*128 + jj];
            s = fmaf(d, d, s);
        }
        block_mse_commit(s, 2.f/131072.f, acc + 1, smem, t);
    }
}

// ====== launch 5: BIGFUSE consistency+inference chain (0..255) + gen decoder mse (256..319)
__global__ __launch_bounds__(256) void bigfuse_kernel(
    const float* __restrict__ out1, const float* __restrict__ encoded,
    const float* __restrict__ ratio_p,
    const float* __restrict__ qw,
    const float* __restrict__ mW1, const float* __restrict__ mb1,
    const float* __restrict__ mW2, const float* __restrict__ mb2,
    const float* __restrict__ mW3, const float* __restrict__ mb3,
    const float* __restrict__ oW1, const float* __restrict__ ob1,
    const float* __restrict__ oW2, const float* __restrict__ ob2,
    const float* __restrict__ oW3, const float* __restrict__ ob3,
    const float* __restrict__ sW1, const float* __restrict__ sb1,
    const float* __restrict__ sW2, const float* __restrict__ sb2,
    const float* __restrict__ sW3, const float* __restrict__ sb3,
    const float* __restrict__ sensory, const float* __restrict__ dec_w,
    const float* __restrict__ dec_b,
    float* __restrict__ out4, float* __restrict__ acc)
{
    __shared__ float smem[5200];
    const int t = threadIdx.x;
    if (blockIdx.x >= 256) {
        // generative pred loss: (out1[:,128:] @ dec_w + dec_b) vs sensory
        const int q = blockIdx.x - 256;
        const int m0 = (q & 31) * 32, n0 = (q >> 5) * 256;
        float4 a4[8];
        gemm_k128_compute(out1 + 128, 256, dec_w, dec_b, 0, 512, m0, n0, t, smem, a4);
        const int c4 = (t & 63) * 4;
        const int r0 = (t >> 6) * 8;
        float s = 0.f;
        #pragma unroll
        for (int i = 0; i < 8; ++i) {
            float4 rv = *(const float4*)&sensory[(size_t)(m0 + r0 + i)*512 + n0 + c4];
            float dx = a4[i].x - rv.x, dy = a4[i].y - rv.y;
            float dz = a4[i].z - rv.z, dw = a4[i].w - rv.w;
            s += dx*dx + dy*dy + dz*dz + dw*dw;
        }
        __syncthreads();
        block_mse_commit(s, 1.f/524288.f, acc + 0, smem, t);
        return;
    }
    float* out1_s = smem;            // 512  (dec_gen_s)
    float* enc_s  = smem + 512;      // 512
    float* out3_s = smem + 1024;     // 1024 (corr_s | corr_e)
    float* ping   = smem + 2048;     // 1024
    float* pong   = smem + 3072;     // 1024
    float* pvar_s = smem + 4096;     // 512
    float* infs_s = smem + 4608;     // 512
    float* sse    = smem + 5120;     // 4
    float* red    = smem + 5124;     // 4
    const int row0 = blockIdx.x * 4;
    {
        int r = (t >> 5) & 3, k4 = (t & 31) * 4;
        *(float4*)&out1_s[r*128 + k4] = *(const float4*)&out1[(size_t)(row0+r)*256 + k4];
        *(float4*)&enc_s[r*128 + k4]  = *(const float4*)&encoded[(size_t)(row0+r)*128 + k4];
    }
    __syncthreads();
    // retrieve #1: (dec_gen_s, encoded) -> out3_s
    layer_n128_dual(qw, out1_s, enc_s, ping, 4, t); __syncthreads();
    layer_n256_r4(mW1, mb1, 128, ping, 128, pong, 1, nullptr, t); __syncthreads();
    layer_n256_r4(mW2, mb2, 256, pong, 256, ping, 1, nullptr, t); __syncthreads();
    layer_n128(mW3, mb3, 256, ping, 256, pong, 128, 0, 4, t); __syncthreads();
    layer_n256_r4(oW1, ob1, 128, pong, 128, ping, 1, nullptr, t); __syncthreads();
    layer_n256_r4(oW2, ob2, 256, ping, 256, pong, 1, nullptr, t); __syncthreads();
    layer_n256_r4(oW3, ob3, 256, pong, 256, out3_s, 0, nullptr, t); __syncthreads();
    // sse per row
    {
        int r = (t >> 5) & 3, k4 = (t & 31) * 4;
        float4 ce = *(const float4*)&out3_s[r*256 + 128 + k4];
        float4 en = *(const float4*)&enc_s[r*128 + k4];
        float dx = ce.x-en.x, dy = ce.y-en.y, dz = ce.z-en.z, dw = ce.w-en.w;
        float ss = dx*dx + dy*dy + dz*dz + dw*dw;
        ss += __shfl_xor(ss, 16); ss += __shfl_xor(ss, 8); ss += __shfl_xor(ss, 4);
        ss += __shfl_xor(ss, 2);  ss += __shfl_xor(ss, 1);
        if ((t & 31) == 0) sse[r] = ss;
    }
    __syncthreads();
    // svar L1: [corr_s | dec_gen_s | sse] @ sW1 -> ping, relu
    {
        const int c4 = (t & 63) * 4;
        const int r = t >> 6;
        float4 a = *(const float4*)&sb1[c4];
        for (int k = 0; k < 128; ++k) {
            float4 w = *(const float4*)&sW1[(size_t)k*256 + c4];
            float xa = out3_s[r*256 + k];
            a.x=fmaf(w.x,xa,a.x); a.y=fmaf(w.y,xa,a.y); a.z=fmaf(w.z,xa,a.z); a.w=fmaf(w.w,xa,a.w);
        }
        for (int k = 0; k < 128; ++k) {
            float4 w = *(const float4*)&sW1[(size_t)(128+k)*256 + c4];
            float xa = out1_s[r*128 + k];
            a.x=fmaf(w.x,xa,a.x); a.y=fmaf(w.y,xa,a.y); a.z=fmaf(w.z,xa,a.z); a.w=fmaf(w.w,xa,a.w);
        }
        {
            float4 w = *(const float4*)&sW1[(size_t)256*256 + c4];
            float xa = sse[r];
            a.x=fmaf(w.x,xa,a.x); a.y=fmaf(w.y,xa,a.y); a.z=fmaf(w.z,xa,a.z); a.w=fmaf(w.w,xa,a.w);
        }
        a.x=fmaxf(a.x,0.f); a.y=fmaxf(a.y,0.f); a.z=fmaxf(a.z,0.f); a.w=fmaxf(a.w,0.f);
        *(float4*)&ping[r*256 + c4] = a;
    }
    __syncthreads();
    layer_n256_r4(sW2, sb2, 256, ping, 256, pong, 1, nullptr, t); __syncthreads();
    layer_n128(sW3, sb3, 256, pong, 256, pvar_s, 128, 0, 4, t); __syncthreads();
    // infs + consistency loss partial
    {
        float ratio = ratio_p[0];
        float ssum = 0.f;
        for (int e = t; e < 512; e += 256) {
            int r = e >> 7, j = e & 127;
            float dgs = out1_s[r*128 + j];
            float cs  = out3_s[r*256 + j];
            float pv  = pvar_s[r*128 + j];
            float delta = (cs - dgs) * ratio * pv;
            infs_s[r*128 + j] = dgs + delta;
            ssum = fmaf(delta, delta, ssum);
        }
        #pragma unroll
        for (int off = 32; off > 0; off >>= 1) ssum += __shfl_down(ssum, off, 64);
        if ((t & 63) == 0) red[t >> 6] = ssum;
    }
    __syncthreads();
    if (t == 0) atomicAdd(acc + 2, (red[0]+red[1]+red[2]+red[3]) * (1.f/131072.f));
    // retrieve #2: (inf_s, 0) -> out4
    layer_n128(qw, nullptr, 128, infs_s, 128, ping, 128, 0, 4, t); __syncthreads();
    layer_n256_r4(mW1, mb1, 128, ping, 128, pong, 1, nullptr, t); __syncthreads();
    layer_n256_r4(mW2, mb2, 256, pong, 256, ping, 1, nullptr, t); __syncthreads();
    layer_n128(mW3, mb3, 256, ping, 256, pong, 128, 0, 4, t); __syncthreads();
    layer_n256_r4(oW1, ob1, 128, pong, 128, ping, 1, nullptr, t); __syncthreads();
    layer_n256_r4(oW2, ob2, 256, ping, 256, pong, 1, nullptr, t); __syncthreads();
    layer_n256_r4(oW3, ob3, 256, pong, 256, ping, 0, nullptr, t); __syncthreads();
    {
        int r = t >> 6, c4 = (t & 63) * 4;
        *(float4*)&out4[(size_t)(row0+r)*256 + c4] = *(const float4*)&ping[r*256 + c4];
    }
}

// ====== launch 6: grad (0..255) + inference decoder mse (256..319) ====
__global__ __launch_bounds__(256) void gradfuse_kernel(
    const float* __restrict__ out4, const float* __restrict__ encoded,
    const float* __restrict__ k_w, const float* __restrict__ v_w,
    const float* __restrict__ mW1, const float* __restrict__ mb1,
    const float* __restrict__ mW2, const float* __restrict__ mb2,
    const float* __restrict__ mW3, const float* __restrict__ mb3,
    const float* __restrict__ T2, const float* __restrict__ T3,
    const float* __restrict__ sensory, const float* __restrict__ dec_w,
    const float* __restrict__ dec_b,
    float* __restrict__ acc, float* __restrict__ out)
{
    __shared__ float smem[6656];
    const int t = threadIdx.x;
    if (blockIdx.x >= 256) {
        const int q = blockIdx.x - 256;
        const int m0 = (q & 31) * 32, n0 = (q >> 5) * 256;
        float4 a4[8];
        gemm_k128_compute(out4 + 128, 256, dec_w, dec_b, 0, 512, m0, n0, t, smem, a4);
        const int c4 = (t & 63) * 4;
        const int r0 = (t >> 6) * 8;
        float s = 0.f;
        #pragma unroll
        for (int i = 0; i < 8; ++i) {
            float4 rv = *(const float4*)&sensory[(size_t)(m0 + r0 + i)*512 + n0 + c4];
            float dx = a4[i].x - rv.x, dy = a4[i].y - rv.y;
            float dz = a4[i].z - rv.z, dw = a4[i].w - rv.w;
            s += dx*dx + dy*dy + dz*dz + dw*dw;
        }
        __syncthreads();
        block_mse_commit(s, 1.f/524288.f, acc + 3, smem, t);
        return;
    }
    float* bufA = smem;          // 512
    float* bufB = smem + 512;    // 512
    float* ks   = smem + 1024;   // 512
    float* vs   = smem + 1536;   // 512
    float* h1   = smem + 2048;   // 1024
    float* h2   = smem + 3072;   // 1024
    float* dob  = smem + 4096;   // 512
    float* dh2  = smem + 4608;   // 1024
    float* dh1  = smem + 5632;   // 1024
    const int row0 = blockIdx.x * 4;

    stage_rows(bufA, out4, 256, row0, 4, t);
    stage_rows(bufB, encoded, 128, row0, 4, t);
    __syncthreads();
    layer_n128_dual(k_w, bufA, bufB, ks, 4, t);
    layer_n128_dual(v_w, bufA, bufB, vs, 4, t);
    __syncthreads();
    layer_n256_r4(mW1, mb1, 128, ks, 128, h1, 1, nullptr, t);
    __syncthreads();
    layer_n256_r4(mW2, mb2, 256, h1, 256, h2, 1, nullptr, t);
    __syncthreads();
    layer_n128(mW3, mb3, 256, h2, 256, dob, 128, 0, 4, t);
    __syncthreads();
    for (int e = t; e < 512; e += 256)
        dob[e] = (dob[e] - vs[e]) * 0.015625f;               // 2/128
    __syncthreads();
    layer_n256_r4(T3, nullptr, 128, dob, 128, dh2, 0, h2, t);
    __syncthreads();
    layer_n256_r4(T2, nullptr, 256, dh2, 256, dh1, 0, h1, t);
    __syncthreads();

    #pragma unroll
    for (int r = 0; r < 4; ++r) {
        const size_t row = row0 + r;
        {   // W1 grad: 128 x 256
            const int c4 = (t & 63) * 4;
            const int i0 = (t >> 6) * 32;
            const float4 dv = *(const float4*)&dh1[r*256 + c4];
            float* p = out + OFF_W1 + row*32768;
            for (int i = i0; i < i0 + 32; ++i) {
                float kv = ks[r*128 + i];
                float4 o; o.x = kv*dv.x; o.y = kv*dv.y; o.z = kv*dv.z; o.w = kv*dv.w;
                *(float4*)&p[(size_t)i*256 + c4] = o;
            }
            out[OFF_B1 + row*256 + t] = dh1[r*256 + t];
        }
        {   // W2 grad: 256 x 256
            const int c4 = (t & 63) * 4;
            const int i0 = (t >> 6) * 64;
            const float4 dv = *(const float4*)&dh2[r*256 + c4];
            float* p = out + OFF_W2 + row*65536;
            for (int i = i0; i < i0 + 64; ++i) {
                float hv = h1[r*256 + i];
                float4 o; o.x = hv*dv.x; o.y = hv*dv.y; o.z = hv*dv.z; o.w = hv*dv.w;
                *(float4*)&p[(size_t)i*256 + c4] = o;
            }
            out[OFF_B2 + row*256 + t] = dh2[r*256 + t];
        }
        {   // W3 grad: 256 x 128
            const int c4 = (t & 31) * 4;
            const int i0 = (t >> 5) * 32;
            const float4 dv = *(const float4*)&dob[r*128 + c4];
            float* p = out + OFF_W3 + row*32768;
            for (int i = i0; i < i0 + 32; ++i) {
                float hv = h2[r*256 + i];
                float4 o; o.x = hv*dv.x; o.y = hv*dv.y; o.z = hv*dv.z; o.w = hv*dv.w;
                *(float4*)&p[(size_t)i*128 + c4] = o;
            }
            if (t < 128) out[OFF_B3 + row*128 + t] = dob[r*128 + t];
        }
    }
}

// ================= launch 7: total =================
__global__ void total_kernel(const float* acc, float* out) {
    if (threadIdx.x == 0)
        out[0] = acc[0] + acc[1] + acc[2] + acc[3];
}

// ================= host =================
extern "C" void kernel_launch(void* const* d_in, const int* in_sizes, int n_in,
                              void* d_out, int out_size, void* d_ws, size_t ws_size,
                              hipStream_t stream)
{
    const float* sensory     = (const float*)d_in[0];
    const float* actions     = (const float*)d_in[1];
    const float* init_hidden = (const float*)d_in[2];
    const float* tW1 = (const float*)d_in[3];  const float* tb1 = (const float*)d_in[4];
    const float* tW2 = (const float*)d_in[5];  const float* tb2 = (const float*)d_in[6];
    const float* tW3 = (const float*)d_in[7];  const float* tb3 = (const float*)d_in[8];
    const float* enc_w = (const float*)d_in[9];  const float* enc_b = (const float*)d_in[10];
    const float* dec_w = (const float*)d_in[11]; const float* dec_b = (const float*)d_in[12];
    const float* q_w = (const float*)d_in[13];
    const float* k_w = (const float*)d_in[14];
    const float* v_w = (const float*)d_in[15];
    const float* mW1 = (const float*)d_in[16]; const float* mb1 = (const float*)d_in[17];
    const float* mW2 = (const float*)d_in[18]; const float* mb2 = (const float*)d_in[19];
    const float* mW3 = (const float*)d_in[20]; const float* mb3 = (const float*)d_in[21];
    const float* oW1 = (const float*)d_in[22]; const float* ob1 = (const float*)d_in[23];
    const float* oW2 = (const float*)d_in[24]; const float* ob2 = (const float*)d_in[25];
    const float* oW3 = (const float*)d_in[26]; const float* ob3 = (const float*)d_in[27];
    const float* sW1 = (const float*)d_in[28]; const float* sb1 = (const float*)d_in[29];
    const float* sW2 = (const float*)d_in[30]; const float* sb2 = (const float*)d_in[31];
    const float* sW3 = (const float*)d_in[32]; const float* sb3 = (const float*)d_in[33];
    const float* ratio = (const float*)d_in[34];
    float* out = (float*)d_out;

    // workspace layout (floats) — total 19,234,832 floats, identical to the proven
    // footprint. tW3T aliases the buffer block; everything in ALIAS is first-written
    // only AFTER gemm_k128 has consumed tW3T (order: prep -> k128 -> scanrel -> ...).
    float* Wsp = (float*)d_ws;
    float* acc   = Wsp;                         // 16 (loss accum 0..3)
    float* ALIAS = Wsp + 16;                    // 2,097,152 floats
    float* structural = ALIAS + 131072;         // 131072
    float* out1 = ALIAS + 262144;               // 262144
    float* out2 = ALIAS + 524288;               // 262144
    float* out4 = ALIAS + 1048576;              // 262144
    float* tW3T = ALIAS;                        // full 2,097,152
    size_t off = 16 + 2097152;
    float* a2      = Wsp + off; off += 131072;
    float* encoded = Wsp + off; off += 131072;
    float* transT  = Wsp + off; off += 16777216;
    float* T2      = Wsp + off; off += 65536;
    float* T3      = Wsp + off; off += 32768;

    // 1. prep: tW3^T, T2, T3, acc zero, actions->a2 MLP, sensory encoder
    prep_kernel<<<801, 256, 0, stream>>>(tW3, mW2, mW3, actions, tW1, tb1, tW2, tb2,
                                         sensory, enc_w, enc_b, tW3T, T2, T3,
                                         acc, a2, encoded);

    // 2. transitions layer 3: dedicated K=128 GEMM -> transT (col-major per step)
    gemm_k128_kernel<<<dim3(32, 64), 256, 0, stream>>>(a2, 128, tW3T, tb3, 1, transT, 16384);

    // 3. RNN scan (8 blocks) + relational retrieve(0,encoded) concurrently (128 blocks)
    scanrel_kernel<<<136, 512, 0, stream>>>(transT, init_hidden, structural, encoded,
        q_w, mW1, mb1, mW2, mb2, mW3, mb3, oW1, ob1, oW2, ob2, oW3, ob3, out2);

    // 4. generative retrieve(structural,0) + relational mse
    genmse_kernel<<<1152, 256, 0, stream>>>(structural,
        q_w, mW1, mb1, mW2, mb2, mW3, mb3, oW1, ob1, oW2, ob2, oW3, ob3,
        out1, out2, acc);

    // 5. consistency+inference chain (retrieve->svar->infs->retrieve) + generative decoder mse
    bigfuse_kernel<<<320, 256, 0, stream>>>(out1, encoded, ratio,
        q_w, mW1, mb1, mW2, mb2, mW3, mb3, oW1, ob1, oW2, ob2, oW3, ob3,
        sW1, sb1, sW2, sb2, sW3, sb3, sensory, dec_w, dec_b, out4, acc);

    // 6. fast-weight grads + inference decoder mse
    gradfuse_kernel<<<320, 256, 0, stream>>>(out4, encoded, k_w, v_w,
        mW1, mb1, mW2, mb2, mW3, mb3, T2, T3, sensory, dec_w, dec_b, acc, out);

    // 7. total
    total_kernel<<<1, 64, 0, stream>>>(acc, out);
}

// Round 6
// 1321.029 us; speedup vs baseline: 1.1607x; 1.0122x over previous
//
#include <hip/hip_runtime.h>
#include <hip/hip_bf16.h>

// ---------------- output layout constants (floats) ----------------
constexpr size_t OFF_W1 = 1;
constexpr size_t OFF_B1 = OFF_W1 + (size_t)1024*32768;
constexpr size_t OFF_W2 = OFF_B1 + (size_t)1024*256;
constexpr size_t OFF_B2 = OFF_W2 + (size_t)1024*65536;
constexpr size_t OFF_W3 = OFF_B2 + (size_t)1024*256;
constexpr size_t OFF_B3 = OFF_W3 + (size_t)1024*32768;

// ================= fused-MLP building blocks (proven) =================
__device__ __forceinline__ void layer_n256_r8(
    const float* __restrict__ W, const float* __restrict__ bias, int K,
    const float* __restrict__ x, int xs, float* __restrict__ y, int relu, int t)
{
    const int c4 = (t & 63) * 4;
    const int r0 = (t >> 6) * 2;
    float4 a0 = bias ? *(const float4*)&bias[c4] : make_float4(0.f,0.f,0.f,0.f);
    float4 a1 = a0;
    const float* x0 = x + r0 * xs;
    const float* x1 = x0 + xs;
    for (int k = 0; k < K; ++k) {
        float4 w = *(const float4*)&W[(size_t)k*256 + c4];
        float xa = x0[k], xb = x1[k];
        a0.x = fmaf(w.x, xa, a0.x); a0.y = fmaf(w.y, xa, a0.y);
        a0.z = fmaf(w.z, xa, a0.z); a0.w = fmaf(w.w, xa, a0.w);
        a1.x = fmaf(w.x, xb, a1.x); a1.y = fmaf(w.y, xb, a1.y);
        a1.z = fmaf(w.z, xb, a1.z); a1.w = fmaf(w.w, xb, a1.w);
    }
    if (relu) {
        a0.x=fmaxf(a0.x,0.f); a0.y=fmaxf(a0.y,0.f); a0.z=fmaxf(a0.z,0.f); a0.w=fmaxf(a0.w,0.f);
        a1.x=fmaxf(a1.x,0.f); a1.y=fmaxf(a1.y,0.f); a1.z=fmaxf(a1.z,0.f); a1.w=fmaxf(a1.w,0.f);
    }
    *(float4*)&y[r0*256 + c4] = a0;
    *(float4*)&y[(r0+1)*256 + c4] = a1;
}

__device__ __forceinline__ void layer_n256_r4(
    const float* __restrict__ W, const float* __restrict__ bias, int K,
    const float* __restrict__ x, int xs, float* __restrict__ y, int relu,
    const float* __restrict__ mask, int t)
{
    const int c4 = (t & 63) * 4;
    const int r = t >> 6;
    float4 a = bias ? *(const float4*)&bias[c4] : make_float4(0.f,0.f,0.f,0.f);
    const float* xr = x + r * xs;
    for (int k = 0; k < K; ++k) {
        float4 w = *(const float4*)&W[(size_t)k*256 + c4];
        float xa = xr[k];
        a.x = fmaf(w.x, xa, a.x); a.y = fmaf(w.y, xa, a.y);
        a.z = fmaf(w.z, xa, a.z); a.w = fmaf(w.w, xa, a.w);
    }
    if (relu) {
        a.x=fmaxf(a.x,0.f); a.y=fmaxf(a.y,0.f); a.z=fmaxf(a.z,0.f); a.w=fmaxf(a.w,0.f);
    }
    if (mask) {
        float4 m = *(const float4*)&mask[r*256 + c4];
        a.x = (m.x > 0.f) ? a.x : 0.f; a.y = (m.y > 0.f) ? a.y : 0.f;
        a.z = (m.z > 0.f) ? a.z : 0.f; a.w = (m.w > 0.f) ? a.w : 0.f;
    }
    *(float4*)&y[r*256 + c4] = a;
}

__device__ __forceinline__ void layer_n128(
    const float* __restrict__ W, const float* __restrict__ bias, int K,
    const float* __restrict__ x, int xs, float* __restrict__ y, int ys, int relu,
    int rows, int t)
{
    const int c4 = (t & 31) * 4;
    int r = t >> 5; if (rows == 4) r &= 3;
    float4 a = bias ? *(const float4*)&bias[c4] : make_float4(0.f,0.f,0.f,0.f);
    const float* xr = x + r * xs;
    for (int k = 0; k < K; ++k) {
        float4 w = *(const float4*)&W[(size_t)k*128 + c4];
        float xa = xr[k];
        a.x = fmaf(w.x, xa, a.x); a.y = fmaf(w.y, xa, a.y);
        a.z = fmaf(w.z, xa, a.z); a.w = fmaf(w.w, xa, a.w);
    }
    if (relu) {
        a.x=fmaxf(a.x,0.f); a.y=fmaxf(a.y,0.f); a.z=fmaxf(a.z,0.f); a.w=fmaxf(a.w,0.f);
    }
    *(float4*)&y[r*ys + c4] = a;
}

__device__ __forceinline__ void layer_n128_dual(
    const float* __restrict__ W,
    const float* __restrict__ xA, const float* __restrict__ xB,
    float* __restrict__ y, int rows, int t)
{
    const int c4 = (t & 31) * 4;
    int r = t >> 5; if (rows == 4) r &= 3;
    float4 a = make_float4(0.f,0.f,0.f,0.f);
    const float* xa_ = xA + r * 128;
    const float* xb_ = xB + r * 128;
    for (int k = 0; k < 128; ++k) {
        float4 w = *(const float4*)&W[(size_t)k*128 + c4];
        float v = xa_[k];
        a.x = fmaf(w.x, v, a.x); a.y = fmaf(w.y, v, a.y);
        a.z = fmaf(w.z, v, a.z); a.w = fmaf(w.w, v, a.w);
    }
    for (int k = 0; k < 128; ++k) {
        float4 w = *(const float4*)&W[(size_t)(128+k)*128 + c4];
        float v = xb_[k];
        a.x = fmaf(w.x, v, a.x); a.y = fmaf(w.y, v, a.y);
        a.z = fmaf(w.z, v, a.z); a.w = fmaf(w.w, v, a.w);
    }
    *(float4*)&y[r*128 + c4] = a;
}

// reduce helper: block-sum of s (256 threads), result via atomicAdd(accum, total*scale)
// NOTE: caller must __syncthreads() before the next write to `red`.
__device__ __forceinline__ void block_mse_commit(float s, float scale,
                                                 float* __restrict__ accum,
                                                 float* __restrict__ red, int t)
{
    #pragma unroll
    for (int off = 32; off > 0; off >>= 1) s += __shfl_down(s, off, 64);
    if ((t & 63) == 0) red[t >> 6] = s;
    __syncthreads();
    if (t == 0) atomicAdd(accum, (red[0]+red[1]+red[2]+red[3]) * scale);
}

// decoder-MSE: (ret[:,128:] @ dec_w + dec_b) vs sensory rows, 4 rows, commit to accum
__device__ __forceinline__ void dec_mse(
    const float* __restrict__ ret,          // 4x256 LDS
    const float* __restrict__ sensory, int row0,
    const float* __restrict__ dec_w, const float* __restrict__ dec_b,
    float* __restrict__ accum, float* __restrict__ red, int t)
{
    const int c4 = (t & 127) * 4;
    const int rb = (t >> 7) * 2;
    float4 a0 = *(const float4*)&dec_b[c4];
    float4 a1 = a0;
    const float* x0 = ret + rb*256 + 128;
    const float* x1 = x0 + 256;
    for (int k = 0; k < 128; ++k) {
        float4 w = *(const float4*)&dec_w[(size_t)k*512 + c4];
        float xa = x0[k], xb = x1[k];
        a0.x = fmaf(w.x, xa, a0.x); a0.y = fmaf(w.y, xa, a0.y);
        a0.z = fmaf(w.z, xa, a0.z); a0.w = fmaf(w.w, xa, a0.w);
        a1.x = fmaf(w.x, xb, a1.x); a1.y = fmaf(w.y, xb, a1.y);
        a1.z = fmaf(w.z, xb, a1.z); a1.w = fmaf(w.w, xb, a1.w);
    }
    float4 s0 = *(const float4*)&sensory[(size_t)(row0+rb)*512 + c4];
    float4 s1 = *(const float4*)&sensory[(size_t)(row0+rb+1)*512 + c4];
    float dx0 = a0.x-s0.x, dy0 = a0.y-s0.y, dz0 = a0.z-s0.z, dw0 = a0.w-s0.w;
    float dx1 = a1.x-s1.x, dy1 = a1.y-s1.y, dz1 = a1.z-s1.z, dw1 = a1.w-s1.w;
    float s = dx0*dx0 + dy0*dy0 + dz0*dz0 + dw0*dw0
            + dx1*dx1 + dy1*dy1 + dz1*dz1 + dw1*dw1;
    block_mse_commit(s, 1.f/524288.f, accum, red, t);
}

// ================= launch 1: prep (tW3^T, T2, T3, acc zero, a1->a2 MLP, encoder) ====
// blocks 0..255: tW3 tiles; 256..511: T2; 512..639: T3; 640: zero;
// 641..768: a12 MLP (8 rows each); 769..800: encoder GEMM
__global__ __launch_bounds__(256) void prep_kernel(
    const float* __restrict__ tW3,
    const float* __restrict__ mW2, const float* __restrict__ mW3,
    const float* __restrict__ actions,
    const float* __restrict__ tW1, const float* __restrict__ tb1,
    const float* __restrict__ tW2, const float* __restrict__ tb2,
    const float* __restrict__ sensory,
    const float* __restrict__ enc_w, const float* __restrict__ enc_b,
    float* __restrict__ tW3T, float* __restrict__ T2, float* __restrict__ T3,
    float* __restrict__ acc, float* __restrict__ a2, float* __restrict__ encoded)
{
    __shared__ float smem[64*129];
    const int t = threadIdx.x;
    const int bid = blockIdx.x;
    if (bid < 256) {
        const int k = bid >> 1, i0 = (bid & 1) * 64;
        const size_t base = (size_t)k << 14;
        for (int l = t; l < 8192; l += 256) {
            int ii = l >> 7, jj = l & 127;
            smem[ii*129 + jj] = tW3[base + (size_t)(i0+ii)*128 + jj];
        }
        __syncthreads();
        for (int l = t; l < 8192; l += 256) {
            int jj = l >> 6, ii = l & 63;
            tW3T[base + (size_t)jj*128 + i0 + ii] = smem[ii*129 + jj];
        }
    } else if (bid < 512) {
        const int c = bid - 256;
        T2[(size_t)c*256 + t] = mW2[(size_t)t*256 + c];
    } else if (bid < 640) {
        const int c = bid - 512;
        T3[(size_t)c*256 + t] = mW3[(size_t)t*128 + c];
    } else if (bid == 640) {
        if (t < 16) acc[t] = 0.f;
    } else if (bid < 769) {
        float* bufAct = smem;            // 256
        float* ping   = smem + 256;      // 1024
        float* pong   = smem + 1280;     // 1024
        const int row0 = (bid - 641) * 8;
        if (t < 64) {
            int r = t >> 3, c4 = (t & 7) * 4;
            *(float4*)&bufAct[r*32 + c4] =
                *(const float4*)&actions[(size_t)(row0 + r)*32 + c4];
        }
        __syncthreads();
        layer_n128(tW1, tb1, 32, bufAct, 32, ping, 128, 1, 8, t);
        __syncthreads();
        layer_n128(tW2, tb2, 128, ping, 128, pong, 128, 1, 8, t);
        __syncthreads();
        {
            int r = t >> 5, c4 = (t & 31) * 4;
            *(float4*)&a2[(size_t)(row0 + r)*128 + c4] = *(const float4*)&pong[r*128 + c4];
        }
    } else {
        // encoder: sensory(1024x512) @ enc_w(512x128) + enc_b -> encoded
        const int q = bid - 769;              // 0..31
        const int m0 = (q & 15) * 64, n0 = (q >> 4) * 64;
        float (*As)[65] = (float(*)[65])smem;
        float (*Ws)[65] = (float(*)[65])(smem + 16*65);
        const int tx = t & 15, ty = t >> 4;
        float a4[4][4] = {};
        for (int k0 = 0; k0 < 512; k0 += 16) {
            for (int l = t; l < 1024; l += 256) {
                int mm = l >> 4, kk = l & 15;
                As[kk][mm] = sensory[(size_t)(m0+mm)*512 + k0 + kk];
            }
            for (int l = t; l < 1024; l += 256) {
                int kk = l >> 6, nn = l & 63;
                Ws[kk][nn] = enc_w[(size_t)(k0+kk)*128 + n0 + nn];
            }
            __syncthreads();
            #pragma unroll
            for (int kk = 0; kk < 16; ++kk) {
                float a[4], b[4];
                #pragma unroll
                for (int i=0;i<4;i++) a[i] = As[kk][ty*4+i];
                #pragma unroll
                for (int j=0;j<4;j++) b[j] = Ws[kk][tx*4+j];
                #pragma unroll
                for (int i=0;i<4;i++)
                    #pragma unroll
                    for (int j=0;j<4;j++)
                        a4[i][j] = fmaf(a[i], b[j], a4[i][j]);
            }
            __syncthreads();
        }
        #pragma unroll
        for (int i=0;i<4;i++){
            int gm = m0 + ty*4 + i;
            #pragma unroll
            for (int j=0;j<4;j++){
                int gn = n0 + tx*4 + j;
                encoded[(size_t)gm*128 + gn] = a4[i][j] + enc_b[gn];
            }
        }
    }
}

// ====== launch 2: K=128 GEMM, 32x256 tiles (proven round-4 form; bias transposed) ======
__global__ __launch_bounds__(256) void gemm_k128_kernel(
    const float* __restrict__ A, int lda, const float* __restrict__ W,
    const float* __restrict__ bias, float* __restrict__ C, int N)
{
    __shared__ float As[128*36];
    const int t = threadIdx.x;
    const int m0 = blockIdx.x * 32, n0 = blockIdx.y * 256;
    for (int l = t; l < 4096; l += 256) {
        int r = l >> 7, k = l & 127;
        As[k*36 + r] = A[(size_t)(m0 + r)*lda + k];
    }
    __syncthreads();
    const int c4 = (t & 63) * 4;
    const int r0 = (t >> 6) * 8;
    float4 bv;
    {   // bias stored transposed: bias[(n&127)*128 + (n>>7)]
        const int n = n0 + c4;
        const int j = n >> 7, i = n & 127;
        bv.x = bias[(size_t)(i+0)*128 + j];
        bv.y = bias[(size_t)(i+1)*128 + j];
        bv.z = bias[(size_t)(i+2)*128 + j];
        bv.w = bias[(size_t)(i+3)*128 + j];
    }
    float4 acc[8];
    #pragma unroll
    for (int i = 0; i < 8; ++i) acc[i] = bv;
    const float* Wp = W + (size_t)n0 + c4;
    #pragma unroll 4
    for (int k = 0; k < 128; ++k) {
        float4 w = *(const float4*)&Wp[(size_t)k*N];
        float a[8];
        *(float4*)&a[0] = *(const float4*)&As[k*36 + r0];
        *(float4*)&a[4] = *(const float4*)&As[k*36 + r0 + 4];
        #pragma unroll
        for (int i = 0; i < 8; ++i) {
            acc[i].x = fmaf(w.x, a[i], acc[i].x);
            acc[i].y = fmaf(w.y, a[i], acc[i].y);
            acc[i].z = fmaf(w.z, a[i], acc[i].z);
            acc[i].w = fmaf(w.w, a[i], acc[i].w);
        }
    }
    #pragma unroll
    for (int i = 0; i < 8; ++i)
        *(float4*)&C[(size_t)(m0 + r0 + i)*N + n0 + c4] = acc[i];
}

// ================= launch 3: scan (blocks 0..7) + relational retrieve (8..135) ======
// (proven round-4 form: depth-1 prefetch)
__global__ __launch_bounds__(512) void scanrel_kernel(
    const float* __restrict__ transT,
    const float* __restrict__ init_hidden,
    float* __restrict__ structural,
    const float* __restrict__ encoded,
    const float* __restrict__ qw,
    const float* __restrict__ mW1, const float* __restrict__ mb1,
    const float* __restrict__ mW2, const float* __restrict__ mb2,
    const float* __restrict__ mW3, const float* __restrict__ mb3,
    const float* __restrict__ oW1, const float* __restrict__ ob1,
    const float* __restrict__ oW2, const float* __restrict__ ob2,
    const float* __restrict__ oW3, const float* __restrict__ ob3,
    float* __restrict__ out2)
{
    __shared__ float smem[5120];
    const int tid = threadIdx.x;
    if (blockIdx.x < 8) {
        float* h  = smem;        // 128
        float* ws = smem + 128;  // 8
        const int b = blockIdx.x;
        const int j = tid >> 2, p = tid & 3;
        const int i0 = p * 32;

        if (tid < 32) {
            float4 v = *(const float4*)&init_hidden[tid*4];
            float ss = v.x*v.x + v.y*v.y + v.z*v.z + v.w*v.w;
            ss += __shfl_xor(ss, 16); ss += __shfl_xor(ss, 8); ss += __shfl_xor(ss, 4);
            ss += __shfl_xor(ss, 2);  ss += __shfl_xor(ss, 1);
            float inv = 1.f / fmaxf(sqrtf(ss), 1e-12f);
            v.x *= inv; v.y *= inv; v.z *= inv; v.w *= inv;
            *(float4*)&h[tid*4] = v;
        }
        __syncthreads();

        const size_t bbase = ((size_t)b) << 21;
        const int lane_off = j*128 + i0;
        float4 cur[8], nxt[8];
        {
            const float* T0 = transT + bbase + lane_off;
            #pragma unroll
            for (int r = 0; r < 8; ++r) cur[r] = *(const float4*)&T0[r*4];
        }
        for (int t = 0; t < 128; ++t) {
            const int tn = (t < 127) ? t + 1 : 127;
            const float* Tn = transT + bbase + ((size_t)tn << 14) + lane_off;
            #pragma unroll
            for (int r = 0; r < 8; ++r) nxt[r] = *(const float4*)&Tn[r*4];

            float4 a = make_float4(0.f, 0.f, 0.f, 0.f);
            #pragma unroll
            for (int r = 0; r < 8; ++r) {
                float4 hv = *(const float4*)&h[i0 + r*4];
                a.x = fmaf(hv.x, cur[r].x, a.x);
                a.y = fmaf(hv.y, cur[r].y, a.y);
                a.z = fmaf(hv.z, cur[r].z, a.z);
                a.w = fmaf(hv.w, cur[r].w, a.w);
            }
            float s = (a.x + a.y) + (a.z + a.w);
            s += __shfl_xor(s, 1);
            s += __shfl_xor(s, 2);
            float v = fmaxf(s, 0.f);
            float q = v * v;
            q += __shfl_xor(q, 4);  q += __shfl_xor(q, 8);
            q += __shfl_xor(q, 16); q += __shfl_xor(q, 32);
            if ((tid & 63) == 0) ws[tid >> 6] = q;
            __syncthreads();
            float ss = ((ws[0]+ws[1]) + (ws[2]+ws[3])) + ((ws[4]+ws[5]) + (ws[6]+ws[7]));
            float inv = 1.f / fmaxf(sqrtf(ss), 1e-12f);
            float hv = v * inv;
            __syncthreads();
            if (p == 0) h[j] = hv;
            else if (p == 1) structural[(((size_t)(b*128 + t)) << 7) + j] = hv;
            __syncthreads();
            #pragma unroll
            for (int r = 0; r < 8; ++r) cur[r] = nxt[r];
        }
    } else {
        float* bufB = smem;           // 1024
        float* ping = smem + 1024;    // 2048
        float* pong = smem + 3072;    // 2048
        const int row0 = (blockIdx.x - 8) * 8;
        const bool act = (tid < 256);
        const int t = tid;
        if (act) {
            int r = t >> 5, k4 = (t & 31) * 4;
            *(float4*)&bufB[r*128 + k4] =
                *(const float4*)&encoded[(size_t)(row0 + r)*128 + k4];
        }
        __syncthreads();
        if (act) layer_n128(qw + (size_t)128*128, nullptr, 128, bufB, 128, ping, 128, 0, 8, t);
        __syncthreads();
        if (act) layer_n256_r8(mW1, mb1, 128, ping, 128, pong, 1, t);
        __syncthreads();
        if (act) layer_n256_r8(mW2, mb2, 256, pong, 256, ping, 1, t);
        __syncthreads();
        if (act) layer_n128(mW3, mb3, 256, ping, 256, pong, 128, 0, 8, t);
        __syncthreads();
        if (act) layer_n256_r8(oW1, ob1, 128, pong, 128, ping, 1, t);
        __syncthreads();
        if (act) layer_n256_r8(oW2, ob2, 256, ping, 256, pong, 1, t);
        __syncthreads();
        if (act) layer_n256_r8(oW3, ob3, 256, pong, 256, ping, 0, t);
        __syncthreads();
        if (act) {
            for (int e = t; e < 512; e += 256) {
                int r = e >> 6, c = (e & 63) * 4;
                *(float4*)&out2[(size_t)(row0+r)*256 + c] = *(const float4*)&ping[r*256 + c];
            }
        }
    }
}

// ====== launch 4: MEGA — per-4-row: gen retrieve + gen-dec MSE + rel MSE +
//        consistency chain + inf-dec MSE + fast-weight grads (all row-local) ======
__global__ __launch_bounds__(256) void mega_kernel(
    const float* __restrict__ structural, const float* __restrict__ encoded,
    const float* __restrict__ out2, const float* __restrict__ sensory,
    const float* __restrict__ ratio_p,
    const float* __restrict__ qw,
    const float* __restrict__ mW1, const float* __restrict__ mb1,
    const float* __restrict__ mW2, const float* __restrict__ mb2,
    const float* __restrict__ mW3, const float* __restrict__ mb3,
    const float* __restrict__ oW1, const float* __restrict__ ob1,
    const float* __restrict__ oW2, const float* __restrict__ ob2,
    const float* __restrict__ oW3, const float* __restrict__ ob3,
    const float* __restrict__ sW1, const float* __restrict__ sb1,
    const float* __restrict__ sW2, const float* __restrict__ sb2,
    const float* __restrict__ sW3, const float* __restrict__ sb3,
    const float* __restrict__ k_w, const float* __restrict__ v_w,
    const float* __restrict__ T2, const float* __restrict__ T3,
    const float* __restrict__ dec_w, const float* __restrict__ dec_b,
    float* __restrict__ acc, float* __restrict__ out)
{
    __shared__ float smem[9736];
    float* enc_s    = smem;          // 512 (whole kernel)
    float* struct_s = smem + 512;    // 512 (until rel-mse)
    float* ping     = smem + 1024;   // 1024 (grad: dh1)
    float* pong     = smem + 2048;   // 1024
    float* ret1     = smem + 3072;   // 1024 (gen out; later inf out = out4)
    float* xa128    = smem + 4096;   // 512  (dec_gen_s; later final_s)
    float* out3_s   = smem + 4608;   // 1024 (grad: dh2)
    float* pvar_s   = smem + 5632;   // 512  (grad: dob)
    float* infs_s   = smem + 6144;   // 512
    float* ks       = smem + 6656;   // 512
    float* vs       = smem + 7168;   // 512
    float* h1       = smem + 7680;   // 1024
    float* h2       = smem + 8704;   // 1024
    float* sse      = smem + 9728;   // 4
    float* red      = smem + 9732;   // 4
    const int t = threadIdx.x;
    const int row0 = blockIdx.x * 4;

    // P0: stage structural + encoded rows
    {
        int r = (t >> 5) & 3, k4 = (t & 31) * 4;
        *(float4*)&struct_s[r*128 + k4] = *(const float4*)&structural[(size_t)(row0+r)*128 + k4];
        *(float4*)&enc_s[r*128 + k4]    = *(const float4*)&encoded[(size_t)(row0+r)*128 + k4];
    }
    __syncthreads();
    // P1: generative retrieve(structural, 0) -> ret1 (4x256)
    layer_n128(qw, nullptr, 128, struct_s, 128, ping, 128, 0, 4, t); __syncthreads();
    layer_n256_r4(mW1, mb1, 128, ping, 128, pong, 1, nullptr, t); __syncthreads();
    layer_n256_r4(mW2, mb2, 256, pong, 256, ping, 1, nullptr, t); __syncthreads();
    layer_n128(mW3, mb3, 256, ping, 256, pong, 128, 0, 4, t); __syncthreads();
    layer_n256_r4(oW1, ob1, 128, pong, 128, ping, 1, nullptr, t); __syncthreads();
    layer_n256_r4(oW2, ob2, 256, ping, 256, pong, 1, nullptr, t); __syncthreads();
    layer_n256_r4(oW3, ob3, 256, pong, 256, ret1, 0, nullptr, t); __syncthreads();
    // P1b: copy dec_gen_s -> xa128; relational MSE (out2 vs structural, x2)
    {
        float relsum = 0.f;
        for (int e = t; e < 512; e += 256) {
            int r = e >> 7, c = e & 127;
            xa128[e] = ret1[r*256 + c];
            float d = out2[(size_t)(row0+r)*256 + c] - struct_s[r*128 + c];
            relsum = fmaf(d, d, relsum);
        }
        block_mse_commit(relsum, 2.f/131072.f, acc + 1, red, t);
    }
    __syncthreads();
    // P2: generative decoder MSE
    dec_mse(ret1, sensory, row0, dec_w, dec_b, acc + 0, red, t);
    __syncthreads();
    // P3: retrieve #1 (dec_gen_s, encoded) -> out3_s
    layer_n128_dual(qw, xa128, enc_s, ping, 4, t); __syncthreads();
    layer_n256_r4(mW1, mb1, 128, ping, 128, pong, 1, nullptr, t); __syncthreads();
    layer_n256_r4(mW2, mb2, 256, pong, 256, ping, 1, nullptr, t); __syncthreads();
    layer_n128(mW3, mb3, 256, ping, 256, pong, 128, 0, 4, t); __syncthreads();
    layer_n256_r4(oW1, ob1, 128, pong, 128, ping, 1, nullptr, t); __syncthreads();
    layer_n256_r4(oW2, ob2, 256, ping, 256, pong, 1, nullptr, t); __syncthreads();
    layer_n256_r4(oW3, ob3, 256, pong, 256, out3_s, 0, nullptr, t); __syncthreads();
    // P4: sse per row; svar MLP -> pvar_s
    {
        int r = (t >> 5) & 3, k4 = (t & 31) * 4;
        float4 ce = *(const float4*)&out3_s[r*256 + 128 + k4];
        float4 en = *(const float4*)&enc_s[r*128 + k4];
        float dx = ce.x-en.x, dy = ce.y-en.y, dz = ce.z-en.z, dw = ce.w-en.w;
        float ss = dx*dx + dy*dy + dz*dz + dw*dw;
        ss += __shfl_xor(ss, 16); ss += __shfl_xor(ss, 8); ss += __shfl_xor(ss, 4);
        ss += __shfl_xor(ss, 2);  ss += __shfl_xor(ss, 1);
        if ((t & 31) == 0) sse[r] = ss;
    }
    __syncthreads();
    {   // svar L1: [corr_s | dec_gen_s | sse] @ sW1 -> ping, relu
        const int c4 = (t & 63) * 4;
        const int r = t >> 6;
        float4 a = *(const float4*)&sb1[c4];
        for (int k = 0; k < 128; ++k) {
            float4 w = *(const float4*)&sW1[(size_t)k*256 + c4];
            float xa = out3_s[r*256 + k];
            a.x=fmaf(w.x,xa,a.x); a.y=fmaf(w.y,xa,a.y); a.z=fmaf(w.z,xa,a.z); a.w=fmaf(w.w,xa,a.w);
        }
        for (int k = 0; k < 128; ++k) {
            float4 w = *(const float4*)&sW1[(size_t)(128+k)*256 + c4];
            float xa = xa128[r*128 + k];
            a.x=fmaf(w.x,xa,a.x); a.y=fmaf(w.y,xa,a.y); a.z=fmaf(w.z,xa,a.z); a.w=fmaf(w.w,xa,a.w);
        }
        {
            float4 w = *(const float4*)&sW1[(size_t)256*256 + c4];
            float xa = sse[r];
            a.x=fmaf(w.x,xa,a.x); a.y=fmaf(w.y,xa,a.y); a.z=fmaf(w.z,xa,a.z); a.w=fmaf(w.w,xa,a.w);
        }
        a.x=fmaxf(a.x,0.f); a.y=fmaxf(a.y,0.f); a.z=fmaxf(a.z,0.f); a.w=fmaxf(a.w,0.f);
        *(float4*)&ping[r*256 + c4] = a;
    }
    __syncthreads();
    layer_n256_r4(sW2, sb2, 256, ping, 256, pong, 1, nullptr, t); __syncthreads();
    layer_n128(sW3, sb3, 256, pong, 256, pvar_s, 128, 0, 4, t); __syncthreads();
    // P5: infs + consistency loss
    {
        float ratio = ratio_p[0];
        float ssum = 0.f;
        for (int e = t; e < 512; e += 256) {
            int r = e >> 7, j = e & 127;
            float dgs = xa128[r*128 + j];
            float cs  = out3_s[r*256 + j];
            float pv  = pvar_s[r*128 + j];
            float delta = (cs - dgs) * ratio * pv;
            infs_s[r*128 + j] = dgs + delta;
            ssum = fmaf(delta, delta, ssum);
        }
        block_mse_commit(ssum, 1.f/131072.f, acc + 2, red, t);
    }
    __syncthreads();
    // P6: retrieve #2 (inf_s, 0) -> ret1 (= out4)
    layer_n128(qw, nullptr, 128, infs_s, 128, ping, 128, 0, 4, t); __syncthreads();
    layer_n256_r4(mW1, mb1, 128, ping, 128, pong, 1, nullptr, t); __syncthreads();
    layer_n256_r4(mW2, mb2, 256, pong, 256, ping, 1, nullptr, t); __syncthreads();
    layer_n128(mW3, mb3, 256, ping, 256, pong, 128, 0, 4, t); __syncthreads();
    layer_n256_r4(oW1, ob1, 128, pong, 128, ping, 1, nullptr, t); __syncthreads();
    layer_n256_r4(oW2, ob2, 256, ping, 256, pong, 1, nullptr, t); __syncthreads();
    layer_n256_r4(oW3, ob3, 256, pong, 256, ret1, 0, nullptr, t); __syncthreads();
    // P7: inference decoder MSE
    dec_mse(ret1, sensory, row0, dec_w, dec_b, acc + 3, red, t);
    __syncthreads();
    // P8: copy final_s -> xa128
    for (int e = t; e < 512; e += 256) {
        int r = e >> 7, c = e & 127;
        xa128[e] = ret1[r*256 + c];
    }
    __syncthreads();
    // P9: fast-weight grads
    float* dob = pvar_s;   // reuse (dead)
    float* dh2 = out3_s;   // reuse (dead)
    float* dh1 = ping;     // reuse (dead)
    layer_n128_dual(k_w, xa128, enc_s, ks, 4, t);
    layer_n128_dual(v_w, xa128, enc_s, vs, 4, t);
    __syncthreads();
    layer_n256_r4(mW1, mb1, 128, ks, 128, h1, 1, nullptr, t);
    __syncthreads();
    layer_n256_r4(mW2, mb2, 256, h1, 256, h2, 1, nullptr, t);
    __syncthreads();
    layer_n128(mW3, mb3, 256, h2, 256, dob, 128, 0, 4, t);
    __syncthreads();
    for (int e = t; e < 512; e += 256)
        dob[e] = (dob[e] - vs[e]) * 0.015625f;               // 2/128
    __syncthreads();
    layer_n256_r4(T3, nullptr, 128, dob, 128, dh2, 0, h2, t);
    __syncthreads();
    layer_n256_r4(T2, nullptr, 256, dh2, 256, dh1, 0, h1, t);
    __syncthreads();
    #pragma unroll
    for (int r = 0; r < 4; ++r) {
        const size_t row = row0 + r;
        {   // W1 grad: 128 x 256
            const int c4 = (t & 63) * 4;
            const int i0 = (t >> 6) * 32;
            const float4 dv = *(const float4*)&dh1[r*256 + c4];
            float* p = out + OFF_W1 + row*32768;
            for (int i = i0; i < i0 + 32; ++i) {
                float kv = ks[r*128 + i];
                float4 o; o.x = kv*dv.x; o.y = kv*dv.y; o.z = kv*dv.z; o.w = kv*dv.w;
                *(float4*)&p[(size_t)i*256 + c4] = o;
            }
            out[OFF_B1 + row*256 + t] = dh1[r*256 + t];
        }
        {   // W2 grad: 256 x 256
            const int c4 = (t & 63) * 4;
            const int i0 = (t >> 6) * 64;
            const float4 dv = *(const float4*)&dh2[r*256 + c4];
            float* p = out + OFF_W2 + row*65536;
            for (int i = i0; i < i0 + 64; ++i) {
                float hv = h1[r*256 + i];
                float4 o; o.x = hv*dv.x; o.y = hv*dv.y; o.z = hv*dv.z; o.w = hv*dv.w;
                *(float4*)&p[(size_t)i*256 + c4] = o;
            }
            out[OFF_B2 + row*256 + t] = dh2[r*256 + t];
        }
        {   // W3 grad: 256 x 128
            const int c4 = (t & 31) * 4;
            const int i0 = (t >> 5) * 32;
            const float4 dv = *(const float4*)&dob[r*128 + c4];
            float* p = out + OFF_W3 + row*32768;
            for (int i = i0; i < i0 + 32; ++i) {
                float hv = h2[r*256 + i];
                float4 o; o.x = hv*dv.x; o.y = hv*dv.y; o.z = hv*dv.z; o.w = hv*dv.w;
                *(float4*)&p[(size_t)i*128 + c4] = o;
            }
            if (t < 128) out[OFF_B3 + row*128 + t] = dob[r*128 + t];
        }
    }
}

// ================= launch 5: total =================
__global__ void total_kernel(const float* acc, float* out) {
    if (threadIdx.x == 0)
        out[0] = acc[0] + acc[1] + acc[2] + acc[3];
}

// ================= host =================
extern "C" void kernel_launch(void* const* d_in, const int* in_sizes, int n_in,
                              void* d_out, int out_size, void* d_ws, size_t ws_size,
                              hipStream_t stream)
{
    const float* sensory     = (const float*)d_in[0];
    const float* actions     = (const float*)d_in[1];
    const float* init_hidden = (const float*)d_in[2];
    const float* tW1 = (const float*)d_in[3];  const float* tb1 = (const float*)d_in[4];
    const float* tW2 = (const float*)d_in[5];  const float* tb2 = (const float*)d_in[6];
    const float* tW3 = (const float*)d_in[7];  const float* tb3 = (const float*)d_in[8];
    const float* enc_w = (const float*)d_in[9];  const float* enc_b = (const float*)d_in[10];
    const float* dec_w = (const float*)d_in[11]; const float* dec_b = (const float*)d_in[12];
    const float* q_w = (const float*)d_in[13];
    const float* k_w = (const float*)d_in[14];
    const float* v_w = (const float*)d_in[15];
    const float* mW1 = (const float*)d_in[16]; const float* mb1 = (const float*)d_in[17];
    const float* mW2 = (const float*)d_in[18]; const float* mb2 = (const float*)d_in[19];
    const float* mW3 = (const float*)d_in[20]; const float* mb3 = (const float*)d_in[21];
    const float* oW1 = (const float*)d_in[22]; const float* ob1 = (const float*)d_in[23];
    const float* oW2 = (const float*)d_in[24]; const float* ob2 = (const float*)d_in[25];
    const float* oW3 = (const float*)d_in[26]; const float* ob3 = (const float*)d_in[27];
    const float* sW1 = (const float*)d_in[28]; const float* sb1 = (const float*)d_in[29];
    const float* sW2 = (const float*)d_in[30]; const float* sb2 = (const float*)d_in[31];
    const float* sW3 = (const float*)d_in[32]; const float* sb3 = (const float*)d_in[33];
    const float* ratio = (const float*)d_in[34];
    float* out = (float*)d_out;

    // workspace layout (floats) — footprint identical to the proven runs (19,234,832).
    // tW3T aliases the buffer block; everything in ALIAS is first-written only AFTER
    // the trans GEMM consumed tW3T (order: prep -> gemm -> scanrel -> mega).
    float* Wsp = (float*)d_ws;
    float* acc   = Wsp;                         // 16 (loss accum 0..3)
    float* ALIAS = Wsp + 16;                    // 2,097,152 floats
    float* structural = ALIAS + 131072;         // 131072
    float* out2 = ALIAS + 524288;               // 262144
    float* tW3T = ALIAS;                        // full 2,097,152
    size_t off = 16 + 2097152;
    float* a2      = Wsp + off; off += 131072;
    float* encoded = Wsp + off; off += 131072;
    float* transT  = Wsp + off; off += 16777216;
    float* T2      = Wsp + off; off += 65536;
    float* T3      = Wsp + off; off += 32768;

    // 1. prep: tW3^T, T2, T3, acc zero, actions->a2 MLP, sensory encoder
    prep_kernel<<<801, 256, 0, stream>>>(tW3, mW2, mW3, actions, tW1, tb1, tW2, tb2,
                                         sensory, enc_w, enc_b, tW3T, T2, T3,
                                         acc, a2, encoded);

    // 2. transitions layer 3: K=128 GEMM (proven 32-row tiles) -> transT
    gemm_k128_kernel<<<dim3(32, 64), 256, 0, stream>>>(a2, 128, tW3T, tb3, transT, 16384);

    // 3. RNN scan (8 blocks) + relational retrieve (128 blocks)
    scanrel_kernel<<<136, 512, 0, stream>>>(transT, init_hidden, structural, encoded,
        q_w, mW1, mb1, mW2, mb2, mW3, mb3, oW1, ob1, oW2, ob2, oW3, ob3, out2);

    // 4. MEGA: all row-local tail work in one 256-block launch
    mega_kernel<<<256, 256, 0, stream>>>(structural, encoded, out2, sensory, ratio,
        q_w, mW1, mb1, mW2, mb2, mW3, mb3, oW1, ob1, oW2, ob2, oW3, ob3,
        sW1, sb1, sW2, sb2, sW3, sb3, k_w, v_w, T2, T3, dec_w, dec_b, acc, out);

    // 5. total
    total_kernel<<<1, 64, 0, stream>>>(acc, out);
}